// Round 4
// baseline (501.428 us; speedup 1.0000x reference)
//
#include <hip/hip_runtime.h>
#include <hip/hip_bf16.h>
#include <math.h>

#define E_N 200000
#define R_N 1000
#define D 128
#define NT 200000
#define NE (2*NT)
#define KDIM 300
#define KP 320
#define BETA 0.3f
#define ALPHA_L 0.2f
#define SCB 1024

typedef __attribute__((ext_vector_type(8))) short short8;
typedef __attribute__((ext_vector_type(4))) float f32x4v;
typedef __attribute__((ext_vector_type(4))) unsigned short ushort4v;

__device__ inline short bfc(float f) {
  __hip_bfloat16 b = __float2bfloat16(f);
  return *reinterpret_cast<short*>(&b);
}
__device__ inline float b2f(unsigned short u) {
  return __uint_as_float((unsigned)u << 16);
}

// ---------------------------------------------------------------------------
// Pack W[300][128] -> bf16 fragment-order, zero-padded to K=320.
// Element ((s*8+f)*64 + l)*8 + j = W[s*32 + (l>>4)*8 + j][f*16 + (l&15)]
// ---------------------------------------------------------------------------
__global__ __launch_bounds__(256) void k_prep_w(
    const float* __restrict__ W, short* __restrict__ WtG)
{
  int e = blockIdx.x * 256 + threadIdx.x;
  if (e >= D * KP) return;
  int j = e & 7;
  int l = (e >> 3) & 63;
  int fi = e >> 9;
  int s = fi >> 3, f = fi & 7;
  int k = s * 32 + (l >> 4) * 8 + j;
  int c = f * 16 + (l & 15);
  float v = (k < KDIM) ? W[(size_t)k * D + c] : 0.f;
  WtG[e] = bfc(v);
}

// ---------------------------------------------------------------------------
// name = A[E,300] @ W + b via bf16 MFMA; no LDS (B-frags stream from L2).
// Block 256/4 waves, tile 128 rows; wave = 32 rows x 128 cols.
// Emits f32 name and bf16 name16.
// ---------------------------------------------------------------------------
__global__ __launch_bounds__(256) void k_name_mfma(
    const float* __restrict__ A, const short* __restrict__ WtG,
    const float* __restrict__ b,
    float* __restrict__ out, short* __restrict__ out16)
{
  const int tid = threadIdx.x;
  const int wid = tid >> 6;
  const int l   = tid & 63;
  const int lc  = l & 15;
  const int kb  = l >> 4;
  const int rowbase = blockIdx.x * 128 + wid * 32;

  float bv[8];
#pragma unroll
  for (int f = 0; f < 8; f++) bv[f] = b[f * 16 + lc];

  f32x4v acc[2][8];
#pragma unroll
  for (int rf = 0; rf < 2; rf++)
#pragma unroll
    for (int f = 0; f < 8; f++) acc[rf][f] = (f32x4v){0.f, 0.f, 0.f, 0.f};

  int r0 = rowbase + lc;
  int r1 = rowbase + 16 + lc;
  int rl0 = (r0 < E_N) ? r0 : (E_N - 1);
  int rl1 = (r1 < E_N) ? r1 : (E_N - 1);
  const float* pa0 = A + (size_t)rl0 * KDIM + kb * 8;
  const float* pa1 = A + (size_t)rl1 * KDIM + kb * 8;

  float4 c00 = *(const float4*)(pa0 + 0);
  float4 c01 = *(const float4*)(pa0 + 4);
  float4 c10 = *(const float4*)(pa1 + 0);
  float4 c11 = *(const float4*)(pa1 + 4);

#pragma unroll
  for (int s = 0; s < 10; s++) {
    float4 n00, n01, n10, n11;
    if (s < 9) {
      if (s == 8) {
        float4 z = {0.f, 0.f, 0.f, 0.f};
        n00 = (kb <= 1) ? *(const float4*)(pa0 + 288) : z;
        n01 = (kb == 0) ? *(const float4*)(pa0 + 292) : z;
        n10 = (kb <= 1) ? *(const float4*)(pa1 + 288) : z;
        n11 = (kb == 0) ? *(const float4*)(pa1 + 292) : z;
      } else {
        int k = 32 * (s + 1);
        n00 = *(const float4*)(pa0 + k);
        n01 = *(const float4*)(pa0 + k + 4);
        n10 = *(const float4*)(pa1 + k);
        n11 = *(const float4*)(pa1 + k + 4);
      }
    }
    short8 af0, af1;
    af0[0] = bfc(c00.x); af0[1] = bfc(c00.y); af0[2] = bfc(c00.z); af0[3] = bfc(c00.w);
    af0[4] = bfc(c01.x); af0[5] = bfc(c01.y); af0[6] = bfc(c01.z); af0[7] = bfc(c01.w);
    af1[0] = bfc(c10.x); af1[1] = bfc(c10.y); af1[2] = bfc(c10.z); af1[3] = bfc(c10.w);
    af1[4] = bfc(c11.x); af1[5] = bfc(c11.y); af1[6] = bfc(c11.z); af1[7] = bfc(c11.w);
#pragma unroll
    for (int f = 0; f < 8; f++) {
      const short8 bf = *(const short8*)(WtG + ((((s * 8 + f) << 6) + l) << 3));
      acc[0][f] = __builtin_amdgcn_mfma_f32_16x16x32_bf16(af0, bf, acc[0][f], 0, 0, 0);
      acc[1][f] = __builtin_amdgcn_mfma_f32_16x16x32_bf16(af1, bf, acc[1][f], 0, 0, 0);
    }
    c00 = n00; c01 = n01; c10 = n10; c11 = n11;
  }

#pragma unroll
  for (int rf = 0; rf < 2; rf++) {
#pragma unroll
    for (int i = 0; i < 4; i++) {
      int row = rowbase + rf * 16 + kb * 4 + i;
      if (row < E_N) {
#pragma unroll
        for (int f = 0; f < 8; f++) {
          float v = acc[rf][f][i] + bv[f];
          out[(size_t)row * D + f * 16 + lc] = v;
          out16[(size_t)row * D + f * 16 + lc] = bfc(v);
        }
      }
    }
  }
}

// ---------------------------------------------------------------------------
// CSR build
// ---------------------------------------------------------------------------
__global__ __launch_bounds__(256) void k_hist(
    const int* __restrict__ th, const int* __restrict__ tr,
    const int* __restrict__ tt,
    int* __restrict__ relDeg, int* __restrict__ rowDeg)
{
  int i = blockIdx.x * 256 + threadIdx.x;
  if (i >= NT) return;
  atomicAdd(&relDeg[tr[i]], 1);
  atomicAdd(&rowDeg[th[i]], 1);
  atomicAdd(&rowDeg[tt[i]], 1);
}

__global__ __launch_bounds__(SCB) void k_scan_block(
    const int* __restrict__ in, int* __restrict__ out,
    int* __restrict__ part, int n)
{
  __shared__ int buf[SCB];
  int i = blockIdx.x * SCB + threadIdx.x;
  int v = (i < n) ? in[i] : 0;
  buf[threadIdx.x] = v;
  __syncthreads();
  for (int off = 1; off < SCB; off <<= 1) {
    int add = (threadIdx.x >= off) ? buf[threadIdx.x - off] : 0;
    __syncthreads();
    buf[threadIdx.x] += add;
    __syncthreads();
  }
  if (i < n) out[i] = buf[threadIdx.x] - v;
  if (threadIdx.x == SCB - 1 && part) part[blockIdx.x] = buf[SCB - 1];
}

__global__ __launch_bounds__(SCB) void k_scan_add(
    int* __restrict__ out, const int* __restrict__ part, int n)
{
  int i = blockIdx.x * SCB + threadIdx.x;
  if (i < n) out[i] += part[blockIdx.x];
}

__global__ __launch_bounds__(256) void k_scatter(
    const int* __restrict__ th, const int* __restrict__ tr,
    const int* __restrict__ tt,
    int* __restrict__ relOff, int* __restrict__ rowOff,
    int* __restrict__ relIdx, unsigned* __restrict__ edgeCR)
{
  int i = blockIdx.x * 256 + threadIdx.x;
  if (i >= NT) return;
  int h = th[i], r = tr[i], t = tt[i];
  int p = atomicAdd(&relOff[r], 1);
  relIdx[p] = i;
  int pf = atomicAdd(&rowOff[h], 1);
  edgeCR[pf] = (unsigned)t | ((unsigned)r << 18);
  int pb = atomicAdd(&rowOff[t], 1);
  edgeCR[pb] = (unsigned)h | ((unsigned)r << 18);
}

// ---------------------------------------------------------------------------
// per-relation sums (bf16 gathers) + mix GEMM; one block per relation
// ---------------------------------------------------------------------------
__global__ __launch_bounds__(256) void k_rel_fused(
    const short* __restrict__ ent16,
    const int* __restrict__ th, const int* __restrict__ tt,
    const int* __restrict__ relIdx, const int* __restrict__ relOff,
    const float* __restrict__ wL, const float* __restrict__ wR,
    const float* __restrict__ watt,
    float* __restrict__ aR, float* __restrict__ bR)
{
  __shared__ float bufH[8][128];
  __shared__ float bufT[8][128];
  __shared__ float red[2][128];
  int r = blockIdx.x;
  int start = (r == 0) ? 0 : relOff[r - 1];
  int end   = relOff[r];
  int g = threadIdx.x >> 5, q = threadIdx.x & 31;

  float4 aH = {0.f, 0.f, 0.f, 0.f}, aT = {0.f, 0.f, 0.f, 0.f};
  for (int j = start + g; j < end; j += 8) {
    int i = relIdx[j];
    ushort4v eh = *(const ushort4v*)&ent16[(size_t)th[i] * D + q * 4];
    ushort4v et = *(const ushort4v*)&ent16[(size_t)tt[i] * D + q * 4];
    aH.x += b2f(eh[0]); aH.y += b2f(eh[1]); aH.z += b2f(eh[2]); aH.w += b2f(eh[3]);
    aT.x += b2f(et[0]); aT.y += b2f(et[1]); aT.z += b2f(et[2]); aT.w += b2f(et[3]);
  }
  *(float4*)&bufH[g][q * 4] = aH;
  *(float4*)&bufT[g][q * 4] = aT;
  __syncthreads();

  int side = threadIdx.x >> 7;
  int d = threadIdx.x & 127;
  float s = 0.f;
  if (side == 0) {
#pragma unroll
    for (int g2 = 0; g2 < 8; g2++) s += bufH[g2][d];
  } else {
#pragma unroll
    for (int g2 = 0; g2 < 8; g2++) s += bufT[g2][d];
  }
  red[side][d] = s;
  __syncthreads();

  int cntv = end - start;
  float inv = cntv ? 1.f / (float)cntv : 0.f;
  const float* w = side ? wR : wL;
  float acc = 0.f;
#pragma unroll 8
  for (int k = 0; k < D; k++) acc = fmaf(red[side][k], w[k * D + d], acc);
  float rv = fmaxf(acc * inv, 0.f);
  if (side == 0) aR[(size_t)r * D + d] = rv * watt[d];
  else           bR[(size_t)r * D + d] = rv * watt[D + d];
}

// ---------------------------------------------------------------------------
// fused edge attention + aggregation + finalize; bf16 gathers.
// ENT_IS_BASE: layer1, er comes from the f32 base row (ent == base).
// W16: also emit bf16 copy of gat (for next layer's gathers).
// ---------------------------------------------------------------------------
template <bool ENT_IS_BASE, bool W16>
__global__ __launch_bounds__(256) void k_row_edge(
    const short* __restrict__ ent16, const float* __restrict__ base,
    const float* __restrict__ aR, const float* __restrict__ bR,
    const int* __restrict__ rowOff, const unsigned* __restrict__ edgeCR,
    float* __restrict__ gat, short* __restrict__ gat16)
{
  int gg = blockIdx.x * 256 + threadIdx.x;
  int row = gg >> 5;
  int q = gg & 31;
  if (row >= E_N) return;
  int start = (row == 0) ? 0 : rowOff[row - 1];
  int end   = rowOff[row];

  float4 b4 = *(const float4*)&base[(size_t)row * D + q * 4];
  float4 er;
  if (ENT_IS_BASE) {
    er = b4;
  } else {
    ushort4v e = *(const ushort4v*)&ent16[(size_t)row * D + q * 4];
    er.x = b2f(e[0]); er.y = b2f(e[1]); er.z = b2f(e[2]); er.w = b2f(e[3]);
  }
  float4 acc = {0.f, 0.f, 0.f, 0.f};
  float rowsum = 0.f;

  for (int j = start; j < end; j++) {
    unsigned cr = edgeCR[j];
    int col = cr & 0x3FFFF;
    int rel = cr >> 18;
    ushort4v e = *(const ushort4v*)&ent16[(size_t)col * D + q * 4];
    float4 ec;
    ec.x = b2f(e[0]); ec.y = b2f(e[1]); ec.z = b2f(e[2]); ec.w = b2f(e[3]);
    float4 a4 = *(const float4*)&aR[(size_t)rel * D + q * 4];
    float4 c4 = *(const float4*)&bR[(size_t)rel * D + q * 4];
    float p = er.x * a4.x + er.y * a4.y + er.z * a4.z + er.w * a4.w
            + ec.x * c4.x + ec.y * c4.y + ec.z * c4.z + ec.w * c4.w;
#pragma unroll
    for (int m = 16; m >= 1; m >>= 1) p += __shfl_xor(p, m, 64);
    float lk = (p >= 0.f) ? p : ALPHA_L * p;
    float att = expf(-lk);
    acc.x = fmaf(att, ec.x, acc.x);
    acc.y = fmaf(att, ec.y, acc.y);
    acc.z = fmaf(att, ec.z, acc.z);
    acc.w = fmaf(att, ec.w, acc.w);
    rowsum += att;
  }
  float inv = (rowsum == 0.f) ? 0.f : 1.f / rowsum;
  float4 o;
  o.x = b4.x + BETA * fmaxf(acc.x * inv, 0.f);
  o.y = b4.y + BETA * fmaxf(acc.y * inv, 0.f);
  o.z = b4.z + BETA * fmaxf(acc.z * inv, 0.f);
  o.w = b4.w + BETA * fmaxf(acc.w * inv, 0.f);
  *(float4*)&gat[(size_t)row * D + q * 4] = o;
  if (W16) {
    ushort4v u;
    u[0] = (unsigned short)bfc(o.x);
    u[1] = (unsigned short)bfc(o.y);
    u[2] = (unsigned short)bfc(o.z);
    u[3] = (unsigned short)bfc(o.w);
    *(ushort4v*)&gat16[(size_t)row * D + q * 4] = u;
  }
}

// ---------------------------------------------------------------------------
extern "C" void kernel_launch(void* const* d_in, const int* in_sizes, int n_in,
                              void* d_out, int out_size, void* d_ws, size_t ws_size,
                              hipStream_t stream)
{
  const float* embed = (const float*)d_in[0];
  const float* wname = (const float*)d_in[1];
  const float* bname = (const float*)d_in[2];
  const float* wL    = (const float*)d_in[3];
  const float* wR    = (const float*)d_in[4];
  const float* watt  = (const float*)d_in[5];
  const int*   th    = (const int*)d_in[6];
  const int*   tr    = (const int*)d_in[7];
  const int*   tt    = (const int*)d_in[8];
  float* out = (float*)d_out;

  char* ws = (char*)d_ws;
  size_t off = 0;
  auto alloc = [&](size_t bytes) -> void* {
    void* p = ws + off;
    off = (off + bytes + 255) & ~(size_t)255;
    return p;
  };
  float*    name   = (float*)alloc((size_t)E_N * D * 4);
  float*    gat1   = (float*)alloc((size_t)E_N * D * 4);
  short*    name16 = (short*)alloc((size_t)E_N * D * 2);
  short*    gat16  = (short*)alloc((size_t)E_N * D * 2);
  float*    aR     = (float*)alloc((size_t)R_N * D * 4);
  float*    bR     = (float*)alloc((size_t)R_N * D * 4);
  int*      relDeg = (int*)alloc((size_t)R_N * 4);
  int*      relOff = (int*)alloc((size_t)R_N * 4);
  int*      rowDeg = (int*)alloc((size_t)E_N * 4);
  int*      rowOff = (int*)alloc((size_t)E_N * 4);
  int*      relIdx = (int*)alloc((size_t)NT * 4);
  unsigned* edgeCR = (unsigned*)alloc((size_t)NE * 4);
  int*      part   = (int*)alloc((size_t)256 * 4);
  short*    WtG    = (short*)alloc((size_t)D * KP * 2);

  // name embedding GEMM (bf16 MFMA, no LDS)
  k_prep_w<<<(D * KP + 255) / 256, 256, 0, stream>>>(wname, WtG);
  k_name_mfma<<<(E_N + 127) / 128, 256, 0, stream>>>(embed, WtG, bname,
                                                     name, name16);

  // CSR build (layer-invariant)
  hipMemsetAsync(relDeg, 0, (size_t)R_N * 4, stream);
  hipMemsetAsync(rowDeg, 0, (size_t)E_N * 4, stream);
  k_hist<<<(NT + 255) / 256, 256, 0, stream>>>(th, tr, tt, relDeg, rowDeg);
  k_scan_block<<<1, SCB, 0, stream>>>(relDeg, relOff, nullptr, R_N);
  int nblk = (E_N + SCB - 1) / SCB;
  k_scan_block<<<nblk, SCB, 0, stream>>>(rowDeg, rowOff, part, E_N);
  k_scan_block<<<1, SCB, 0, stream>>>(part, part, nullptr, nblk);
  k_scan_add<<<nblk, SCB, 0, stream>>>(rowOff, part, E_N);
  k_scatter<<<(NT + 255) / 256, 256, 0, stream>>>(th, tr, tt, relOff, rowOff,
                                                  relIdx, edgeCR);

  // layer 1: ent = name (base), emit gat1 + gat16
  k_rel_fused<<<R_N, 256, 0, stream>>>(name16, th, tt, relIdx, relOff,
                                       wL, wR, watt, aR, bR);
  k_row_edge<true, true><<<(E_N * 32) / 256, 256, 0, stream>>>(
      name16, name, aR, bR, rowOff, edgeCR, gat1, gat16);

  // layer 2: ent = gat1 (bf16 in gat16), emit out
  k_rel_fused<<<R_N, 256, 0, stream>>>(gat16, th, tt, relIdx, relOff,
                                       wL, wR, watt, aR, bR);
  k_row_edge<false, false><<<(E_N * 32) / 256, 256, 0, stream>>>(
      gat16, name, aR, bR, rowOff, edgeCR, out, nullptr);
}

// Round 5
// 443.133 us; speedup vs baseline: 1.1316x; 1.1316x over previous
//
#include <hip/hip_runtime.h>
#include <hip/hip_bf16.h>
#include <math.h>

#define E_N 200000
#define R_N 1000
#define D 128
#define NT 200000
#define NE (2*NT)
#define KDIM 300
#define KP 320
#define BETA 0.3f
#define ALPHA_L 0.2f
#define SCB 1024
#define RPB 256          // rows per block in name GEMM (64 per wave)

typedef __attribute__((ext_vector_type(8))) short short8;
typedef __attribute__((ext_vector_type(4))) float f32x4v;
typedef __attribute__((ext_vector_type(4))) unsigned short ushort4v;

__device__ inline short bfc(float f) {
  __hip_bfloat16 b = __float2bfloat16(f);
  return *reinterpret_cast<short*>(&b);
}
__device__ inline float b2f(unsigned short u) {
  return __uint_as_float((unsigned)u << 16);
}

// ---------------------------------------------------------------------------
// Pack W[300][128] -> bf16 fragment-order, zero-padded to K=320.
// Element ((s*8+f)*64 + l)*8 + j = W[s*32 + (l>>4)*8 + j][f*16 + (l&15)]
// ---------------------------------------------------------------------------
__global__ __launch_bounds__(256) void k_prep_w(
    const float* __restrict__ W, short* __restrict__ WtG)
{
  int e = blockIdx.x * 256 + threadIdx.x;
  if (e >= D * KP) return;
  int j = e & 7;
  int l = (e >> 3) & 63;
  int fi = e >> 9;
  int s = fi >> 3, f = fi & 7;
  int k = s * 32 + (l >> 4) * 8 + j;
  int c = f * 16 + (l & 15);
  float v = (k < KDIM) ? W[(size_t)k * D + c] : 0.f;
  WtG[e] = bfc(v);
}

// ---------------------------------------------------------------------------
// name16 = bf16(A[E,300] @ W + b) via bf16 MFMA. W staged in LDS (80KB,
// linear copy; B-frag ds_read_b128 at lane*16 = conflict-free). 4 waves,
// 64 rows/wave (4 row-frags) for deep A-load ILP. No f32 output.
// ---------------------------------------------------------------------------
__global__ __launch_bounds__(256) void k_name_mfma(
    const float* __restrict__ A, const short* __restrict__ WtG,
    const float* __restrict__ b, short* __restrict__ out16)
{
  __shared__ short Wt[D * KP];    // 81920 B

  const int tid = threadIdx.x;
  {  // linear W stage (layout identical to global)
    const uint4* src = (const uint4*)WtG;
    uint4* dst = (uint4*)Wt;
#pragma unroll
    for (int i = 0; i < 20; i++) dst[i * 256 + tid] = src[i * 256 + tid];
  }
  __syncthreads();

  const int wid = tid >> 6;
  const int l   = tid & 63;
  const int lc  = l & 15;
  const int kb  = l >> 4;
  const int rowbase = blockIdx.x * RPB + wid * 64;

  float bv[8];
#pragma unroll
  for (int f = 0; f < 8; f++) bv[f] = b[f * 16 + lc];

  f32x4v acc[4][8];
#pragma unroll
  for (int i = 0; i < 4; i++)
#pragma unroll
    for (int f = 0; f < 8; f++) acc[i][f] = (f32x4v){0.f, 0.f, 0.f, 0.f};

  const float* pa[4];
#pragma unroll
  for (int i = 0; i < 4; i++) {
    int r = rowbase + i * 16 + lc;
    int rl = (r < E_N) ? r : (E_N - 1);
    pa[i] = A + (size_t)rl * KDIM + kb * 8;
  }

  float4 cur[4][2];
#pragma unroll
  for (int i = 0; i < 4; i++) {
    cur[i][0] = *(const float4*)(pa[i] + 0);
    cur[i][1] = *(const float4*)(pa[i] + 4);
  }

#pragma unroll
  for (int s = 0; s < 10; s++) {
    // convert current step to bf16 fragments
    short8 af[4];
#pragma unroll
    for (int i = 0; i < 4; i++) {
      af[i][0] = bfc(cur[i][0].x); af[i][1] = bfc(cur[i][0].y);
      af[i][2] = bfc(cur[i][0].z); af[i][3] = bfc(cur[i][0].w);
      af[i][4] = bfc(cur[i][1].x); af[i][5] = bfc(cur[i][1].y);
      af[i][6] = bfc(cur[i][1].z); af[i][7] = bfc(cur[i][1].w);
    }
    // prefetch next step into cur
    if (s < 9) {
      if (s == 8) {
        float4 z = {0.f, 0.f, 0.f, 0.f};
#pragma unroll
        for (int i = 0; i < 4; i++) {
          cur[i][0] = (kb <= 1) ? *(const float4*)(pa[i] + 288) : z;
          cur[i][1] = (kb == 0) ? *(const float4*)(pa[i] + 292) : z;
        }
      } else {
        int k = 32 * (s + 1);
#pragma unroll
        for (int i = 0; i < 4; i++) {
          cur[i][0] = *(const float4*)(pa[i] + k);
          cur[i][1] = *(const float4*)(pa[i] + k + 4);
        }
      }
    }
    // 32 MFMAs on this K-step
#pragma unroll
    for (int f = 0; f < 8; f++) {
      const short8 bf = *(const short8*)((const char*)Wt + (((s * 8 + f) << 6) + l) * 16);
#pragma unroll
      for (int i = 0; i < 4; i++)
        acc[i][f] = __builtin_amdgcn_mfma_f32_16x16x32_bf16(af[i], bf, acc[i][f], 0, 0, 0);
    }
  }

  // epilogue: C frag layout col = lane&15, row = kb*4 + ii
#pragma unroll
  for (int i = 0; i < 4; i++) {
#pragma unroll
    for (int ii = 0; ii < 4; ii++) {
      int row = rowbase + i * 16 + kb * 4 + ii;
      if (row < E_N) {
#pragma unroll
        for (int f = 0; f < 8; f++)
          out16[(size_t)row * D + f * 16 + lc] = bfc(acc[i][f][ii] + bv[f]);
      }
    }
  }
}

// ---------------------------------------------------------------------------
// CSR build
// ---------------------------------------------------------------------------
__global__ __launch_bounds__(256) void k_hist(
    const int* __restrict__ th, const int* __restrict__ tr,
    const int* __restrict__ tt,
    int* __restrict__ relDeg, int* __restrict__ rowDeg)
{
  int i = blockIdx.x * 256 + threadIdx.x;
  if (i >= NT) return;
  atomicAdd(&relDeg[tr[i]], 1);
  atomicAdd(&rowDeg[th[i]], 1);
  atomicAdd(&rowDeg[tt[i]], 1);
}

__global__ __launch_bounds__(SCB) void k_scan_block(
    const int* __restrict__ in, int* __restrict__ out,
    int* __restrict__ part, int n)
{
  __shared__ int buf[SCB];
  int i = blockIdx.x * SCB + threadIdx.x;
  int v = (i < n) ? in[i] : 0;
  buf[threadIdx.x] = v;
  __syncthreads();
  for (int off = 1; off < SCB; off <<= 1) {
    int add = (threadIdx.x >= off) ? buf[threadIdx.x - off] : 0;
    __syncthreads();
    buf[threadIdx.x] += add;
    __syncthreads();
  }
  if (i < n) out[i] = buf[threadIdx.x] - v;
  if (threadIdx.x == SCB - 1 && part) part[blockIdx.x] = buf[SCB - 1];
}

__global__ __launch_bounds__(SCB) void k_scan_add(
    int* __restrict__ out, const int* __restrict__ part, int n)
{
  int i = blockIdx.x * SCB + threadIdx.x;
  if (i < n) out[i] += part[blockIdx.x];
}

__global__ __launch_bounds__(256) void k_scatter(
    const int* __restrict__ th, const int* __restrict__ tr,
    const int* __restrict__ tt,
    int* __restrict__ relOff, int* __restrict__ rowOff,
    int* __restrict__ relIdx, unsigned* __restrict__ edgeCR)
{
  int i = blockIdx.x * 256 + threadIdx.x;
  if (i >= NT) return;
  int h = th[i], r = tr[i], t = tt[i];
  int p = atomicAdd(&relOff[r], 1);
  relIdx[p] = i;
  int pf = atomicAdd(&rowOff[h], 1);
  edgeCR[pf] = (unsigned)t | ((unsigned)r << 18);
  int pb = atomicAdd(&rowOff[t], 1);
  edgeCR[pb] = (unsigned)h | ((unsigned)r << 18);
}

// ---------------------------------------------------------------------------
// per-relation sums (bf16 gathers) + mix GEMM; one block per relation
// ---------------------------------------------------------------------------
__global__ __launch_bounds__(256) void k_rel_fused(
    const short* __restrict__ ent16,
    const int* __restrict__ th, const int* __restrict__ tt,
    const int* __restrict__ relIdx, const int* __restrict__ relOff,
    const float* __restrict__ wL, const float* __restrict__ wR,
    const float* __restrict__ watt,
    float* __restrict__ aR, float* __restrict__ bR)
{
  __shared__ float bufH[8][128];
  __shared__ float bufT[8][128];
  __shared__ float red[2][128];
  int r = blockIdx.x;
  int start = (r == 0) ? 0 : relOff[r - 1];
  int end   = relOff[r];
  int g = threadIdx.x >> 5, q = threadIdx.x & 31;

  float4 aH = {0.f, 0.f, 0.f, 0.f}, aT = {0.f, 0.f, 0.f, 0.f};
  for (int j = start + g; j < end; j += 8) {
    int i = relIdx[j];
    ushort4v eh = *(const ushort4v*)&ent16[(size_t)th[i] * D + q * 4];
    ushort4v et = *(const ushort4v*)&ent16[(size_t)tt[i] * D + q * 4];
    aH.x += b2f(eh[0]); aH.y += b2f(eh[1]); aH.z += b2f(eh[2]); aH.w += b2f(eh[3]);
    aT.x += b2f(et[0]); aT.y += b2f(et[1]); aT.z += b2f(et[2]); aT.w += b2f(et[3]);
  }
  *(float4*)&bufH[g][q * 4] = aH;
  *(float4*)&bufT[g][q * 4] = aT;
  __syncthreads();

  int side = threadIdx.x >> 7;
  int d = threadIdx.x & 127;
  float s = 0.f;
  if (side == 0) {
#pragma unroll
    for (int g2 = 0; g2 < 8; g2++) s += bufH[g2][d];
  } else {
#pragma unroll
    for (int g2 = 0; g2 < 8; g2++) s += bufT[g2][d];
  }
  red[side][d] = s;
  __syncthreads();

  int cntv = end - start;
  float inv = cntv ? 1.f / (float)cntv : 0.f;
  const float* w = side ? wR : wL;
  float acc = 0.f;
#pragma unroll 8
  for (int k = 0; k < D; k++) acc = fmaf(red[side][k], w[k * D + d], acc);
  float rv = fmaxf(acc * inv, 0.f);
  if (side == 0) aR[(size_t)r * D + d] = rv * watt[d];
  else           bR[(size_t)r * D + d] = rv * watt[D + d];
}

// ---------------------------------------------------------------------------
// fused edge attention + aggregation + finalize; all-bf16 entity reads.
// ENT_IS_BASE: er == base row (layer 1). WF32: write f32 out (final layer),
// else write bf16 gat16.
// ---------------------------------------------------------------------------
template <bool ENT_IS_BASE, bool WF32>
__global__ __launch_bounds__(256) void k_row_edge(
    const short* __restrict__ ent16, const short* __restrict__ base16,
    const float* __restrict__ aR, const float* __restrict__ bR,
    const int* __restrict__ rowOff, const unsigned* __restrict__ edgeCR,
    float* __restrict__ outf, short* __restrict__ out16)
{
  int gg = blockIdx.x * 256 + threadIdx.x;
  int row = gg >> 5;
  int q = gg & 31;
  if (row >= E_N) return;
  int start = (row == 0) ? 0 : rowOff[row - 1];
  int end   = rowOff[row];

  ushort4v bu = *(const ushort4v*)&base16[(size_t)row * D + q * 4];
  float4 b4;
  b4.x = b2f(bu[0]); b4.y = b2f(bu[1]); b4.z = b2f(bu[2]); b4.w = b2f(bu[3]);
  float4 er;
  if (ENT_IS_BASE) {
    er = b4;
  } else {
    ushort4v e = *(const ushort4v*)&ent16[(size_t)row * D + q * 4];
    er.x = b2f(e[0]); er.y = b2f(e[1]); er.z = b2f(e[2]); er.w = b2f(e[3]);
  }
  float4 acc = {0.f, 0.f, 0.f, 0.f};
  float rowsum = 0.f;

  for (int j = start; j < end; j++) {
    unsigned cr = edgeCR[j];
    int col = cr & 0x3FFFF;
    int rel = cr >> 18;
    ushort4v e = *(const ushort4v*)&ent16[(size_t)col * D + q * 4];
    float4 ec;
    ec.x = b2f(e[0]); ec.y = b2f(e[1]); ec.z = b2f(e[2]); ec.w = b2f(e[3]);
    float4 a4 = *(const float4*)&aR[(size_t)rel * D + q * 4];
    float4 c4 = *(const float4*)&bR[(size_t)rel * D + q * 4];
    float p = er.x * a4.x + er.y * a4.y + er.z * a4.z + er.w * a4.w
            + ec.x * c4.x + ec.y * c4.y + ec.z * c4.z + ec.w * c4.w;
#pragma unroll
    for (int m = 16; m >= 1; m >>= 1) p += __shfl_xor(p, m, 64);
    float lk = (p >= 0.f) ? p : ALPHA_L * p;
    float att = expf(-lk);
    acc.x = fmaf(att, ec.x, acc.x);
    acc.y = fmaf(att, ec.y, acc.y);
    acc.z = fmaf(att, ec.z, acc.z);
    acc.w = fmaf(att, ec.w, acc.w);
    rowsum += att;
  }
  float inv = (rowsum == 0.f) ? 0.f : 1.f / rowsum;
  float4 o;
  o.x = b4.x + BETA * fmaxf(acc.x * inv, 0.f);
  o.y = b4.y + BETA * fmaxf(acc.y * inv, 0.f);
  o.z = b4.z + BETA * fmaxf(acc.z * inv, 0.f);
  o.w = b4.w + BETA * fmaxf(acc.w * inv, 0.f);
  if (WF32) {
    *(float4*)&outf[(size_t)row * D + q * 4] = o;
  } else {
    ushort4v u;
    u[0] = (unsigned short)bfc(o.x);
    u[1] = (unsigned short)bfc(o.y);
    u[2] = (unsigned short)bfc(o.z);
    u[3] = (unsigned short)bfc(o.w);
    *(ushort4v*)&out16[(size_t)row * D + q * 4] = u;
  }
}

// ---------------------------------------------------------------------------
extern "C" void kernel_launch(void* const* d_in, const int* in_sizes, int n_in,
                              void* d_out, int out_size, void* d_ws, size_t ws_size,
                              hipStream_t stream)
{
  const float* embed = (const float*)d_in[0];
  const float* wname = (const float*)d_in[1];
  const float* bname = (const float*)d_in[2];
  const float* wL    = (const float*)d_in[3];
  const float* wR    = (const float*)d_in[4];
  const float* watt  = (const float*)d_in[5];
  const int*   th    = (const int*)d_in[6];
  const int*   tr    = (const int*)d_in[7];
  const int*   tt    = (const int*)d_in[8];
  float* out = (float*)d_out;

  char* ws = (char*)d_ws;
  size_t off = 0;
  auto alloc = [&](size_t bytes) -> void* {
    void* p = ws + off;
    off = (off + bytes + 255) & ~(size_t)255;
    return p;
  };
  short*    name16 = (short*)alloc((size_t)E_N * D * 2);
  short*    gat16  = (short*)alloc((size_t)E_N * D * 2);
  float*    aR     = (float*)alloc((size_t)R_N * D * 4);
  float*    bR     = (float*)alloc((size_t)R_N * D * 4);
  int*      relDeg = (int*)alloc((size_t)R_N * 4);
  int*      relOff = (int*)alloc((size_t)R_N * 4);
  int*      rowDeg = (int*)alloc((size_t)E_N * 4);
  int*      rowOff = (int*)alloc((size_t)E_N * 4);
  int*      relIdx = (int*)alloc((size_t)NT * 4);
  unsigned* edgeCR = (unsigned*)alloc((size_t)NE * 4);
  int*      part   = (int*)alloc((size_t)256 * 4);
  short*    WtG    = (short*)alloc((size_t)D * KP * 2);

  // name embedding GEMM (bf16 MFMA, W in LDS)
  k_prep_w<<<(D * KP + 255) / 256, 256, 0, stream>>>(wname, WtG);
  k_name_mfma<<<(E_N + RPB - 1) / RPB, 256, 0, stream>>>(embed, WtG, bname,
                                                         name16);

  // CSR build (layer-invariant)
  hipMemsetAsync(relDeg, 0, (size_t)R_N * 4, stream);
  hipMemsetAsync(rowDeg, 0, (size_t)E_N * 4, stream);
  k_hist<<<(NT + 255) / 256, 256, 0, stream>>>(th, tr, tt, relDeg, rowDeg);
  k_scan_block<<<1, SCB, 0, stream>>>(relDeg, relOff, nullptr, R_N);
  int nblk = (E_N + SCB - 1) / SCB;
  k_scan_block<<<nblk, SCB, 0, stream>>>(rowDeg, rowOff, part, E_N);
  k_scan_block<<<1, SCB, 0, stream>>>(part, part, nullptr, nblk);
  k_scan_add<<<nblk, SCB, 0, stream>>>(rowOff, part, E_N);
  k_scatter<<<(NT + 255) / 256, 256, 0, stream>>>(th, tr, tt, relOff, rowOff,
                                                  relIdx, edgeCR);

  // layer 1: ent = base = name16, emit gat16
  k_rel_fused<<<R_N, 256, 0, stream>>>(name16, th, tt, relIdx, relOff,
                                       wL, wR, watt, aR, bR);
  k_row_edge<true, false><<<(E_N * 32) / 256, 256, 0, stream>>>(
      name16, name16, aR, bR, rowOff, edgeCR, nullptr, gat16);

  // layer 2: ent = gat16, base = name16, emit f32 out
  k_rel_fused<<<R_N, 256, 0, stream>>>(gat16, th, tt, relIdx, relOff,
                                       wL, wR, watt, aR, bR);
  k_row_edge<false, true><<<(E_N * 32) / 256, 256, 0, stream>>>(
      gat16, name16, aR, bR, rowOff, edgeCR, out, nullptr);
}

// Round 6
// 395.941 us; speedup vs baseline: 1.2664x; 1.1192x over previous
//
#include <hip/hip_runtime.h>
#include <hip/hip_bf16.h>
#include <math.h>

#define E_N 200000
#define R_N 1000
#define D 128
#define NT 200000
#define NE (2*NT)
#define KDIM 300
#define KP 320
#define BETA 0.3f
#define ALPHA_L 0.2f
#define SCB 1024
#define RPB 128          // rows per block in name GEMM (32 per wave)
#define CHUNK_SHORTS (5 * 8 * 64 * 8)   // 5 K-steps of frag-order W = 40KB

typedef __attribute__((ext_vector_type(8))) short short8;
typedef __attribute__((ext_vector_type(4))) float f32x4v;
typedef __attribute__((ext_vector_type(4))) unsigned short ushort4v;

__device__ inline short bfc(float f) {
  __hip_bfloat16 b = __float2bfloat16(f);
  return *reinterpret_cast<short*>(&b);
}
__device__ inline float b2f(unsigned short u) {
  return __uint_as_float((unsigned)u << 16);
}

// ---------------------------------------------------------------------------
// Pack W[300][128] -> bf16 fragment-order, zero-padded to K=320.
// Element ((s*8+f)*64 + l)*8 + j = W[s*32 + (l>>4)*8 + j][f*16 + (l&15)]
// ---------------------------------------------------------------------------
__global__ __launch_bounds__(256) void k_prep_w(
    const float* __restrict__ W, short* __restrict__ WtG)
{
  int e = blockIdx.x * 256 + threadIdx.x;
  if (e >= D * KP) return;
  int j = e & 7;
  int l = (e >> 3) & 63;
  int fi = e >> 9;
  int s = fi >> 3, f = fi & 7;
  int k = s * 32 + (l >> 4) * 8 + j;
  int c = f * 16 + (l & 15);
  float v = (k < KDIM) ? W[(size_t)k * D + c] : 0.f;
  WtG[e] = bfc(v);
}

// ---------------------------------------------------------------------------
// name16 = bf16(A[E,300] @ W + b). 4 waves x 32 rows; acc = 64 AGPR/wave.
// W staged in LDS in 2 chunks of 40KB (K=160 each) -> 3-4 blocks/CU.
// A prefetched one K-step ahead (reg double-buffer).
// ---------------------------------------------------------------------------
__global__ __launch_bounds__(256, 3) void k_name_mfma(
    const float* __restrict__ A, const short* __restrict__ WtG,
    const float* __restrict__ b, short* __restrict__ out16)
{
  __shared__ short Wt[CHUNK_SHORTS];    // 40960 B

  const int tid = threadIdx.x;
  const int wid = tid >> 6;
  const int l   = tid & 63;
  const int lc  = l & 15;
  const int kb  = l >> 4;
  const int rowbase = blockIdx.x * RPB + wid * 32;

  float bv[8];
#pragma unroll
  for (int f = 0; f < 8; f++) bv[f] = b[f * 16 + lc];

  f32x4v acc[2][8];
#pragma unroll
  for (int i = 0; i < 2; i++)
#pragma unroll
    for (int f = 0; f < 8; f++) acc[i][f] = (f32x4v){0.f, 0.f, 0.f, 0.f};

  const float* pa[2];
#pragma unroll
  for (int i = 0; i < 2; i++) {
    int r = rowbase + i * 16 + lc;
    int rl = (r < E_N) ? r : (E_N - 1);
    pa[i] = A + (size_t)rl * KDIM + kb * 8;
  }

  float4 cur[2][2];
#pragma unroll
  for (int i = 0; i < 2; i++) {
    cur[i][0] = *(const float4*)(pa[i] + 0);
    cur[i][1] = *(const float4*)(pa[i] + 4);
  }

#pragma unroll
  for (int c = 0; c < 2; c++) {
    if (c == 1) __syncthreads();   // protect Wt before restage
    {  // stage chunk c (40KB linear)
      const uint4* src = (const uint4*)(WtG + c * CHUNK_SHORTS);
      uint4* dst = (uint4*)Wt;
#pragma unroll
      for (int i = 0; i < 10; i++) dst[i * 256 + tid] = src[i * 256 + tid];
    }
    __syncthreads();

#pragma unroll
    for (int s5 = 0; s5 < 5; s5++) {
      const int s = c * 5 + s5;
      // convert current A step to bf16 fragments
      short8 af[2];
#pragma unroll
      for (int i = 0; i < 2; i++) {
        af[i][0] = bfc(cur[i][0].x); af[i][1] = bfc(cur[i][0].y);
        af[i][2] = bfc(cur[i][0].z); af[i][3] = bfc(cur[i][0].w);
        af[i][4] = bfc(cur[i][1].x); af[i][5] = bfc(cur[i][1].y);
        af[i][6] = bfc(cur[i][1].z); af[i][7] = bfc(cur[i][1].w);
      }
      // prefetch next A step
      if (s < 9) {
        if (s == 8) {
          float4 z = {0.f, 0.f, 0.f, 0.f};
#pragma unroll
          for (int i = 0; i < 2; i++) {
            cur[i][0] = (kb <= 1) ? *(const float4*)(pa[i] + 288) : z;
            cur[i][1] = (kb == 0) ? *(const float4*)(pa[i] + 292) : z;
          }
        } else {
          int k = 32 * (s + 1);
#pragma unroll
          for (int i = 0; i < 2; i++) {
            cur[i][0] = *(const float4*)(pa[i] + k);
            cur[i][1] = *(const float4*)(pa[i] + k + 4);
          }
        }
      }
      // 16 MFMAs on this K-step
#pragma unroll
      for (int f = 0; f < 8; f++) {
        const short8 bf = *(const short8*)((const char*)Wt + (((s5 * 8 + f) << 6) + l) * 16);
#pragma unroll
        for (int i = 0; i < 2; i++)
          acc[i][f] = __builtin_amdgcn_mfma_f32_16x16x32_bf16(af[i], bf, acc[i][f], 0, 0, 0);
      }
    }
  }

  // epilogue: C frag layout col = lane&15, row = kb*4 + ii
#pragma unroll
  for (int i = 0; i < 2; i++) {
#pragma unroll
    for (int ii = 0; ii < 4; ii++) {
      int row = rowbase + i * 16 + kb * 4 + ii;
      if (row < E_N) {
#pragma unroll
        for (int f = 0; f < 8; f++)
          out16[(size_t)row * D + f * 16 + lc] = bfc(acc[i][f][ii] + bv[f]);
      }
    }
  }
}

// ---------------------------------------------------------------------------
// CSR build
// ---------------------------------------------------------------------------
__global__ __launch_bounds__(256) void k_hist(
    const int* __restrict__ th, const int* __restrict__ tr,
    const int* __restrict__ tt,
    int* __restrict__ relDeg, int* __restrict__ rowDeg)
{
  int i = blockIdx.x * 256 + threadIdx.x;
  if (i >= NT) return;
  atomicAdd(&relDeg[tr[i]], 1);
  atomicAdd(&rowDeg[th[i]], 1);
  atomicAdd(&rowDeg[tt[i]], 1);
}

__global__ __launch_bounds__(SCB) void k_scan_block(
    const int* __restrict__ in, int* __restrict__ out,
    int* __restrict__ part, int n)
{
  __shared__ int buf[SCB];
  int i = blockIdx.x * SCB + threadIdx.x;
  int v = (i < n) ? in[i] : 0;
  buf[threadIdx.x] = v;
  __syncthreads();
  for (int off = 1; off < SCB; off <<= 1) {
    int add = (threadIdx.x >= off) ? buf[threadIdx.x - off] : 0;
    __syncthreads();
    buf[threadIdx.x] += add;
    __syncthreads();
  }
  if (i < n) out[i] = buf[threadIdx.x] - v;
  if (threadIdx.x == SCB - 1 && part) part[blockIdx.x] = buf[SCB - 1];
}

__global__ __launch_bounds__(SCB) void k_scan_add(
    int* __restrict__ out, const int* __restrict__ part, int n)
{
  int i = blockIdx.x * SCB + threadIdx.x;
  if (i < n) out[i] += part[blockIdx.x];
}

__global__ __launch_bounds__(256) void k_scatter(
    const int* __restrict__ th, const int* __restrict__ tr,
    const int* __restrict__ tt,
    int* __restrict__ relOff, int* __restrict__ rowOff,
    int* __restrict__ relIdx, unsigned* __restrict__ edgeCR)
{
  int i = blockIdx.x * 256 + threadIdx.x;
  if (i >= NT) return;
  int h = th[i], r = tr[i], t = tt[i];
  int p = atomicAdd(&relOff[r], 1);
  relIdx[p] = i;
  int pf = atomicAdd(&rowOff[h], 1);
  edgeCR[pf] = (unsigned)t | ((unsigned)r << 18);
  int pb = atomicAdd(&rowOff[t], 1);
  edgeCR[pb] = (unsigned)h | ((unsigned)r << 18);
}

// ---------------------------------------------------------------------------
// per-relation sums (bf16 gathers, 2x unrolled for MLP) + mix GEMM
// ---------------------------------------------------------------------------
__global__ __launch_bounds__(256) void k_rel_fused(
    const short* __restrict__ ent16,
    const int* __restrict__ th, const int* __restrict__ tt,
    const int* __restrict__ relIdx, const int* __restrict__ relOff,
    const float* __restrict__ wL, const float* __restrict__ wR,
    const float* __restrict__ watt,
    float* __restrict__ aR, float* __restrict__ bR)
{
  __shared__ float bufH[8][128];
  __shared__ float bufT[8][128];
  __shared__ float red[2][128];
  int r = blockIdx.x;
  int start = (r == 0) ? 0 : relOff[r - 1];
  int end   = relOff[r];
  int g = threadIdx.x >> 5, q = threadIdx.x & 31;

  float4 aH = {0.f, 0.f, 0.f, 0.f}, aT = {0.f, 0.f, 0.f, 0.f};
  int j = start + g;
  for (; j + 8 < end; j += 16) {
    int i0 = relIdx[j];
    int i1 = relIdx[j + 8];
    ushort4v eh0 = *(const ushort4v*)&ent16[(size_t)th[i0] * D + q * 4];
    ushort4v et0 = *(const ushort4v*)&ent16[(size_t)tt[i0] * D + q * 4];
    ushort4v eh1 = *(const ushort4v*)&ent16[(size_t)th[i1] * D + q * 4];
    ushort4v et1 = *(const ushort4v*)&ent16[(size_t)tt[i1] * D + q * 4];
    aH.x += b2f(eh0[0]) + b2f(eh1[0]); aH.y += b2f(eh0[1]) + b2f(eh1[1]);
    aH.z += b2f(eh0[2]) + b2f(eh1[2]); aH.w += b2f(eh0[3]) + b2f(eh1[3]);
    aT.x += b2f(et0[0]) + b2f(et1[0]); aT.y += b2f(et0[1]) + b2f(et1[1]);
    aT.z += b2f(et0[2]) + b2f(et1[2]); aT.w += b2f(et0[3]) + b2f(et1[3]);
  }
  if (j < end) {
    int i = relIdx[j];
    ushort4v eh = *(const ushort4v*)&ent16[(size_t)th[i] * D + q * 4];
    ushort4v et = *(const ushort4v*)&ent16[(size_t)tt[i] * D + q * 4];
    aH.x += b2f(eh[0]); aH.y += b2f(eh[1]); aH.z += b2f(eh[2]); aH.w += b2f(eh[3]);
    aT.x += b2f(et[0]); aT.y += b2f(et[1]); aT.z += b2f(et[2]); aT.w += b2f(et[3]);
  }
  *(float4*)&bufH[g][q * 4] = aH;
  *(float4*)&bufT[g][q * 4] = aT;
  __syncthreads();

  int side = threadIdx.x >> 7;
  int d = threadIdx.x & 127;
  float s = 0.f;
  if (side == 0) {
#pragma unroll
    for (int g2 = 0; g2 < 8; g2++) s += bufH[g2][d];
  } else {
#pragma unroll
    for (int g2 = 0; g2 < 8; g2++) s += bufT[g2][d];
  }
  red[side][d] = s;
  __syncthreads();

  int cntv = end - start;
  float inv = cntv ? 1.f / (float)cntv : 0.f;
  const float* w = side ? wR : wL;
  float acc = 0.f;
#pragma unroll 8
  for (int k = 0; k < D; k++) acc = fmaf(red[side][k], w[k * D + d], acc);
  float rv = fmaxf(acc * inv, 0.f);
  if (side == 0) aR[(size_t)r * D + d] = rv * watt[d];
  else           bR[(size_t)r * D + d] = rv * watt[D + d];
}

// ---------------------------------------------------------------------------
// fused edge attention + aggregation + finalize; bf16 reads, 2x unrolled.
// ---------------------------------------------------------------------------
template <bool ENT_IS_BASE, bool WF32>
__global__ __launch_bounds__(256) void k_row_edge(
    const short* __restrict__ ent16, const short* __restrict__ base16,
    const float* __restrict__ aR, const float* __restrict__ bR,
    const int* __restrict__ rowOff, const unsigned* __restrict__ edgeCR,
    float* __restrict__ outf, short* __restrict__ out16)
{
  int gg = blockIdx.x * 256 + threadIdx.x;
  int row = gg >> 5;
  int q = gg & 31;
  if (row >= E_N) return;
  int start = (row == 0) ? 0 : rowOff[row - 1];
  int end   = rowOff[row];

  ushort4v bu = *(const ushort4v*)&base16[(size_t)row * D + q * 4];
  float4 b4;
  b4.x = b2f(bu[0]); b4.y = b2f(bu[1]); b4.z = b2f(bu[2]); b4.w = b2f(bu[3]);
  float4 er;
  if (ENT_IS_BASE) {
    er = b4;
  } else {
    ushort4v e = *(const ushort4v*)&ent16[(size_t)row * D + q * 4];
    er.x = b2f(e[0]); er.y = b2f(e[1]); er.z = b2f(e[2]); er.w = b2f(e[3]);
  }
  float4 acc = {0.f, 0.f, 0.f, 0.f};
  float rowsum = 0.f;

  int j = start;
  for (; j + 1 < end; j += 2) {
    unsigned cr0 = edgeCR[j];
    unsigned cr1 = edgeCR[j + 1];
    int col0 = cr0 & 0x3FFFF, rel0 = cr0 >> 18;
    int col1 = cr1 & 0x3FFFF, rel1 = cr1 >> 18;
    ushort4v e0 = *(const ushort4v*)&ent16[(size_t)col0 * D + q * 4];
    ushort4v e1 = *(const ushort4v*)&ent16[(size_t)col1 * D + q * 4];
    float4 a0 = *(const float4*)&aR[(size_t)rel0 * D + q * 4];
    float4 c0 = *(const float4*)&bR[(size_t)rel0 * D + q * 4];
    float4 a1 = *(const float4*)&aR[(size_t)rel1 * D + q * 4];
    float4 c1 = *(const float4*)&bR[(size_t)rel1 * D + q * 4];
    float4 ec0, ec1;
    ec0.x = b2f(e0[0]); ec0.y = b2f(e0[1]); ec0.z = b2f(e0[2]); ec0.w = b2f(e0[3]);
    ec1.x = b2f(e1[0]); ec1.y = b2f(e1[1]); ec1.z = b2f(e1[2]); ec1.w = b2f(e1[3]);
    float p0 = er.x * a0.x + er.y * a0.y + er.z * a0.z + er.w * a0.w
             + ec0.x * c0.x + ec0.y * c0.y + ec0.z * c0.z + ec0.w * c0.w;
    float p1 = er.x * a1.x + er.y * a1.y + er.z * a1.z + er.w * a1.w
             + ec1.x * c1.x + ec1.y * c1.y + ec1.z * c1.z + ec1.w * c1.w;
#pragma unroll
    for (int m = 16; m >= 1; m >>= 1) {
      p0 += __shfl_xor(p0, m, 64);
      p1 += __shfl_xor(p1, m, 64);
    }
    float l0 = (p0 >= 0.f) ? p0 : ALPHA_L * p0;
    float l1 = (p1 >= 0.f) ? p1 : ALPHA_L * p1;
    float att0 = expf(-l0);
    float att1 = expf(-l1);
    acc.x = fmaf(att0, ec0.x, acc.x); acc.y = fmaf(att0, ec0.y, acc.y);
    acc.z = fmaf(att0, ec0.z, acc.z); acc.w = fmaf(att0, ec0.w, acc.w);
    acc.x = fmaf(att1, ec1.x, acc.x); acc.y = fmaf(att1, ec1.y, acc.y);
    acc.z = fmaf(att1, ec1.z, acc.z); acc.w = fmaf(att1, ec1.w, acc.w);
    rowsum += att0 + att1;
  }
  if (j < end) {
    unsigned cr = edgeCR[j];
    int col = cr & 0x3FFFF, rel = cr >> 18;
    ushort4v e = *(const ushort4v*)&ent16[(size_t)col * D + q * 4];
    float4 a4 = *(const float4*)&aR[(size_t)rel * D + q * 4];
    float4 c4 = *(const float4*)&bR[(size_t)rel * D + q * 4];
    float4 ec;
    ec.x = b2f(e[0]); ec.y = b2f(e[1]); ec.z = b2f(e[2]); ec.w = b2f(e[3]);
    float p = er.x * a4.x + er.y * a4.y + er.z * a4.z + er.w * a4.w
            + ec.x * c4.x + ec.y * c4.y + ec.z * c4.z + ec.w * c4.w;
#pragma unroll
    for (int m = 16; m >= 1; m >>= 1) p += __shfl_xor(p, m, 64);
    float lk = (p >= 0.f) ? p : ALPHA_L * p;
    float att = expf(-lk);
    acc.x = fmaf(att, ec.x, acc.x); acc.y = fmaf(att, ec.y, acc.y);
    acc.z = fmaf(att, ec.z, acc.z); acc.w = fmaf(att, ec.w, acc.w);
    rowsum += att;
  }
  float inv = (rowsum == 0.f) ? 0.f : 1.f / rowsum;
  float4 o;
  o.x = b4.x + BETA * fmaxf(acc.x * inv, 0.f);
  o.y = b4.y + BETA * fmaxf(acc.y * inv, 0.f);
  o.z = b4.z + BETA * fmaxf(acc.z * inv, 0.f);
  o.w = b4.w + BETA * fmaxf(acc.w * inv, 0.f);
  if (WF32) {
    *(float4*)&outf[(size_t)row * D + q * 4] = o;
  } else {
    ushort4v u;
    u[0] = (unsigned short)bfc(o.x);
    u[1] = (unsigned short)bfc(o.y);
    u[2] = (unsigned short)bfc(o.z);
    u[3] = (unsigned short)bfc(o.w);
    *(ushort4v*)&out16[(size_t)row * D + q * 4] = u;
  }
}

// ---------------------------------------------------------------------------
extern "C" void kernel_launch(void* const* d_in, const int* in_sizes, int n_in,
                              void* d_out, int out_size, void* d_ws, size_t ws_size,
                              hipStream_t stream)
{
  const float* embed = (const float*)d_in[0];
  const float* wname = (const float*)d_in[1];
  const float* bname = (const float*)d_in[2];
  const float* wL    = (const float*)d_in[3];
  const float* wR    = (const float*)d_in[4];
  const float* watt  = (const float*)d_in[5];
  const int*   th    = (const int*)d_in[6];
  const int*   tr    = (const int*)d_in[7];
  const int*   tt    = (const int*)d_in[8];
  float* out = (float*)d_out;

  char* ws = (char*)d_ws;
  size_t off = 0;
  auto alloc = [&](size_t bytes) -> void* {
    void* p = ws + off;
    off = (off + bytes + 255) & ~(size_t)255;
    return p;
  };
  short*    name16 = (short*)alloc((size_t)E_N * D * 2);
  short*    gat16  = (short*)alloc((size_t)E_N * D * 2);
  float*    aR     = (float*)alloc((size_t)R_N * D * 4);
  float*    bR     = (float*)alloc((size_t)R_N * D * 4);
  int*      relDeg = (int*)alloc((size_t)R_N * 4);
  int*      relOff = (int*)alloc((size_t)R_N * 4);
  int*      rowDeg = (int*)alloc((size_t)E_N * 4);
  int*      rowOff = (int*)alloc((size_t)E_N * 4);
  int*      relIdx = (int*)alloc((size_t)NT * 4);
  unsigned* edgeCR = (unsigned*)alloc((size_t)NE * 4);
  int*      part   = (int*)alloc((size_t)256 * 4);
  short*    WtG    = (short*)alloc((size_t)D * KP * 2);

  // name embedding GEMM (bf16 MFMA, chunked W-LDS)
  k_prep_w<<<(D * KP + 255) / 256, 256, 0, stream>>>(wname, WtG);
  k_name_mfma<<<(E_N + RPB - 1) / RPB, 256, 0, stream>>>(embed, WtG, bname,
                                                         name16);

  // CSR build (layer-invariant)
  hipMemsetAsync(relDeg, 0, (size_t)R_N * 4, stream);
  hipMemsetAsync(rowDeg, 0, (size_t)E_N * 4, stream);
  k_hist<<<(NT + 255) / 256, 256, 0, stream>>>(th, tr, tt, relDeg, rowDeg);
  k_scan_block<<<1, SCB, 0, stream>>>(relDeg, relOff, nullptr, R_N);
  int nblk = (E_N + SCB - 1) / SCB;
  k_scan_block<<<nblk, SCB, 0, stream>>>(rowDeg, rowOff, part, E_N);
  k_scan_block<<<1, SCB, 0, stream>>>(part, part, nullptr, nblk);
  k_scan_add<<<nblk, SCB, 0, stream>>>(rowOff, part, E_N);
  k_scatter<<<(NT + 255) / 256, 256, 0, stream>>>(th, tr, tt, relOff, rowOff,
                                                  relIdx, edgeCR);

  // layer 1: ent = base = name16, emit gat16
  k_rel_fused<<<R_N, 256, 0, stream>>>(name16, th, tt, relIdx, relOff,
                                       wL, wR, watt, aR, bR);
  k_row_edge<true, false><<<(E_N * 32) / 256, 256, 0, stream>>>(
      name16, name16, aR, bR, rowOff, edgeCR, nullptr, gat16);

  // layer 2: ent = gat16, base = name16, emit f32 out
  k_rel_fused<<<R_N, 256, 0, stream>>>(gat16, th, tt, relIdx, relOff,
                                       wL, wR, watt, aR, bR);
  k_row_edge<false, true><<<(E_N * 32) / 256, 256, 0, stream>>>(
      gat16, name16, aR, bR, rowOff, edgeCR, out, nullptr);
}

// Round 7
// 393.312 us; speedup vs baseline: 1.2749x; 1.0067x over previous
//
#include <hip/hip_runtime.h>
#include <hip/hip_bf16.h>
#include <math.h>

#define E_N 200000
#define R_N 1000
#define D 128
#define NT 200000
#define NE (2*NT)
#define KDIM 300
#define KP 320
#define BETA 0.3f
#define ALPHA_L 0.2f
#define SCB 1024
#define RPB 128          // rows per block in name GEMM (32 per wave)
#define CHUNK_SHORTS (5 * 8 * 64 * 8)   // 5 K-steps of frag-order W = 40KB

typedef __attribute__((ext_vector_type(8))) short short8;
typedef __attribute__((ext_vector_type(4))) float f32x4v;
typedef __attribute__((ext_vector_type(4))) unsigned short ushort4v;

__device__ inline short bfc(float f) {
  __hip_bfloat16 b = __float2bfloat16(f);
  return *reinterpret_cast<short*>(&b);
}
__device__ inline float b2f(unsigned short u) {
  return __uint_as_float((unsigned)u << 16);
}

// ---------------------------------------------------------------------------
// zero relDeg + rowDeg (replaces pathologically slow runtime fill kernel)
// grid = 196 blocks x 256 thr, int4 stores
// ---------------------------------------------------------------------------
__global__ __launch_bounds__(256) void k_zero(
    int4* __restrict__ relDeg, int4* __restrict__ rowDeg)
{
  int i = blockIdx.x * 256 + threadIdx.x;
  const int4 z = {0, 0, 0, 0};
  if (i < R_N / 4) relDeg[i] = z;
  if (i < E_N / 4) rowDeg[i] = z;
}

// ---------------------------------------------------------------------------
// Pack W[300][128] -> bf16 fragment-order, zero-padded to K=320.
// Element ((s*8+f)*64 + l)*8 + j = W[s*32 + (l>>4)*8 + j][f*16 + (l&15)]
// ---------------------------------------------------------------------------
__global__ __launch_bounds__(256) void k_prep_w(
    const float* __restrict__ W, short* __restrict__ WtG)
{
  int e = blockIdx.x * 256 + threadIdx.x;
  if (e >= D * KP) return;
  int j = e & 7;
  int l = (e >> 3) & 63;
  int fi = e >> 9;
  int s = fi >> 3, f = fi & 7;
  int k = s * 32 + (l >> 4) * 8 + j;
  int c = f * 16 + (l & 15);
  float v = (k < KDIM) ? W[(size_t)k * D + c] : 0.f;
  WtG[e] = bfc(v);
}

// ---------------------------------------------------------------------------
// name16 = bf16(A[E,300] @ W + b). 4 waves x 32 rows; acc = 64 AGPR/wave.
// W staged in LDS in 2 chunks of 40KB (K=160 each).
// ---------------------------------------------------------------------------
__global__ __launch_bounds__(256, 3) void k_name_mfma(
    const float* __restrict__ A, const short* __restrict__ WtG,
    const float* __restrict__ b, short* __restrict__ out16)
{
  __shared__ short Wt[CHUNK_SHORTS];    // 40960 B

  const int tid = threadIdx.x;
  const int wid = tid >> 6;
  const int l   = tid & 63;
  const int lc  = l & 15;
  const int kb  = l >> 4;
  const int rowbase = blockIdx.x * RPB + wid * 32;

  float bv[8];
#pragma unroll
  for (int f = 0; f < 8; f++) bv[f] = b[f * 16 + lc];

  f32x4v acc[2][8];
#pragma unroll
  for (int i = 0; i < 2; i++)
#pragma unroll
    for (int f = 0; f < 8; f++) acc[i][f] = (f32x4v){0.f, 0.f, 0.f, 0.f};

  const float* pa[2];
#pragma unroll
  for (int i = 0; i < 2; i++) {
    int r = rowbase + i * 16 + lc;
    int rl = (r < E_N) ? r : (E_N - 1);
    pa[i] = A + (size_t)rl * KDIM + kb * 8;
  }

  float4 cur[2][2];
#pragma unroll
  for (int i = 0; i < 2; i++) {
    cur[i][0] = *(const float4*)(pa[i] + 0);
    cur[i][1] = *(const float4*)(pa[i] + 4);
  }

#pragma unroll
  for (int c = 0; c < 2; c++) {
    if (c == 1) __syncthreads();   // protect Wt before restage
    {  // stage chunk c (40KB linear)
      const uint4* src = (const uint4*)(WtG + c * CHUNK_SHORTS);
      uint4* dst = (uint4*)Wt;
#pragma unroll
      for (int i = 0; i < 10; i++) dst[i * 256 + tid] = src[i * 256 + tid];
    }
    __syncthreads();

#pragma unroll
    for (int s5 = 0; s5 < 5; s5++) {
      const int s = c * 5 + s5;
      short8 af[2];
#pragma unroll
      for (int i = 0; i < 2; i++) {
        af[i][0] = bfc(cur[i][0].x); af[i][1] = bfc(cur[i][0].y);
        af[i][2] = bfc(cur[i][0].z); af[i][3] = bfc(cur[i][0].w);
        af[i][4] = bfc(cur[i][1].x); af[i][5] = bfc(cur[i][1].y);
        af[i][6] = bfc(cur[i][1].z); af[i][7] = bfc(cur[i][1].w);
      }
      if (s < 9) {
        if (s == 8) {
          float4 z = {0.f, 0.f, 0.f, 0.f};
#pragma unroll
          for (int i = 0; i < 2; i++) {
            cur[i][0] = (kb <= 1) ? *(const float4*)(pa[i] + 288) : z;
            cur[i][1] = (kb == 0) ? *(const float4*)(pa[i] + 292) : z;
          }
        } else {
          int k = 32 * (s + 1);
#pragma unroll
          for (int i = 0; i < 2; i++) {
            cur[i][0] = *(const float4*)(pa[i] + k);
            cur[i][1] = *(const float4*)(pa[i] + k + 4);
          }
        }
      }
#pragma unroll
      for (int f = 0; f < 8; f++) {
        const short8 bf = *(const short8*)((const char*)Wt + (((s5 * 8 + f) << 6) + l) * 16);
#pragma unroll
        for (int i = 0; i < 2; i++)
          acc[i][f] = __builtin_amdgcn_mfma_f32_16x16x32_bf16(af[i], bf, acc[i][f], 0, 0, 0);
      }
    }
  }

#pragma unroll
  for (int i = 0; i < 2; i++) {
#pragma unroll
    for (int ii = 0; ii < 4; ii++) {
      int row = rowbase + i * 16 + kb * 4 + ii;
      if (row < E_N) {
#pragma unroll
        for (int f = 0; f < 8; f++)
          out16[(size_t)row * D + f * 16 + lc] = bfc(acc[i][f][ii] + bv[f]);
      }
    }
  }
}

// ---------------------------------------------------------------------------
// CSR build
// ---------------------------------------------------------------------------
__global__ __launch_bounds__(256) void k_hist(
    const int* __restrict__ th, const int* __restrict__ tr,
    const int* __restrict__ tt,
    int* __restrict__ relDeg, int* __restrict__ rowDeg)
{
  int i = blockIdx.x * 256 + threadIdx.x;
  if (i >= NT) return;
  atomicAdd(&relDeg[tr[i]], 1);
  atomicAdd(&rowDeg[th[i]], 1);
  atomicAdd(&rowDeg[tt[i]], 1);
}

__global__ __launch_bounds__(SCB) void k_scan_block(
    const int* __restrict__ in, int* __restrict__ out,
    int* __restrict__ part, int n)
{
  __shared__ int buf[SCB];
  int i = blockIdx.x * SCB + threadIdx.x;
  int v = (i < n) ? in[i] : 0;
  buf[threadIdx.x] = v;
  __syncthreads();
  for (int off = 1; off < SCB; off <<= 1) {
    int add = (threadIdx.x >= off) ? buf[threadIdx.x - off] : 0;
    __syncthreads();
    buf[threadIdx.x] += add;
    __syncthreads();
  }
  if (i < n) out[i] = buf[threadIdx.x] - v;
  if (threadIdx.x == SCB - 1 && part) part[blockIdx.x] = buf[SCB - 1];
}

__global__ __launch_bounds__(SCB) void k_scan_add(
    int* __restrict__ out, const int* __restrict__ part, int n)
{
  int i = blockIdx.x * SCB + threadIdx.x;
  if (i < n) out[i] += part[blockIdx.x];
}

__global__ __launch_bounds__(256) void k_scatter(
    const int* __restrict__ th, const int* __restrict__ tr,
    const int* __restrict__ tt,
    int* __restrict__ relOff, int* __restrict__ rowOff,
    int* __restrict__ relIdx, unsigned* __restrict__ edgeCR)
{
  int i = blockIdx.x * 256 + threadIdx.x;
  if (i >= NT) return;
  int h = th[i], r = tr[i], t = tt[i];
  int p = atomicAdd(&relOff[r], 1);
  relIdx[p] = i;
  int pf = atomicAdd(&rowOff[h], 1);
  edgeCR[pf] = (unsigned)t | ((unsigned)r << 18);
  int pb = atomicAdd(&rowOff[t], 1);
  edgeCR[pb] = (unsigned)h | ((unsigned)r << 18);
}

// ---------------------------------------------------------------------------
// per-relation sums (bf16 gathers, 2x unrolled) + mix GEMM
// ---------------------------------------------------------------------------
__global__ __launch_bounds__(256) void k_rel_fused(
    const short* __restrict__ ent16,
    const int* __restrict__ th, const int* __restrict__ tt,
    const int* __restrict__ relIdx, const int* __restrict__ relOff,
    const float* __restrict__ wL, const float* __restrict__ wR,
    const float* __restrict__ watt,
    float* __restrict__ aR, float* __restrict__ bR)
{
  __shared__ float bufH[8][128];
  __shared__ float bufT[8][128];
  __shared__ float red[2][128];
  int r = blockIdx.x;
  int start = (r == 0) ? 0 : relOff[r - 1];
  int end   = relOff[r];
  int g = threadIdx.x >> 5, q = threadIdx.x & 31;

  float4 aH = {0.f, 0.f, 0.f, 0.f}, aT = {0.f, 0.f, 0.f, 0.f};
  int j = start + g;
  for (; j + 8 < end; j += 16) {
    int i0 = relIdx[j];
    int i1 = relIdx[j + 8];
    ushort4v eh0 = *(const ushort4v*)&ent16[(size_t)th[i0] * D + q * 4];
    ushort4v et0 = *(const ushort4v*)&ent16[(size_t)tt[i0] * D + q * 4];
    ushort4v eh1 = *(const ushort4v*)&ent16[(size_t)th[i1] * D + q * 4];
    ushort4v et1 = *(const ushort4v*)&ent16[(size_t)tt[i1] * D + q * 4];
    aH.x += b2f(eh0[0]) + b2f(eh1[0]); aH.y += b2f(eh0[1]) + b2f(eh1[1]);
    aH.z += b2f(eh0[2]) + b2f(eh1[2]); aH.w += b2f(eh0[3]) + b2f(eh1[3]);
    aT.x += b2f(et0[0]) + b2f(et1[0]); aT.y += b2f(et0[1]) + b2f(et1[1]);
    aT.z += b2f(et0[2]) + b2f(et1[2]); aT.w += b2f(et0[3]) + b2f(et1[3]);
  }
  if (j < end) {
    int i = relIdx[j];
    ushort4v eh = *(const ushort4v*)&ent16[(size_t)th[i] * D + q * 4];
    ushort4v et = *(const ushort4v*)&ent16[(size_t)tt[i] * D + q * 4];
    aH.x += b2f(eh[0]); aH.y += b2f(eh[1]); aH.z += b2f(eh[2]); aH.w += b2f(eh[3]);
    aT.x += b2f(et[0]); aT.y += b2f(et[1]); aT.z += b2f(et[2]); aT.w += b2f(et[3]);
  }
  *(float4*)&bufH[g][q * 4] = aH;
  *(float4*)&bufT[g][q * 4] = aT;
  __syncthreads();

  int side = threadIdx.x >> 7;
  int d = threadIdx.x & 127;
  float s = 0.f;
  if (side == 0) {
#pragma unroll
    for (int g2 = 0; g2 < 8; g2++) s += bufH[g2][d];
  } else {
#pragma unroll
    for (int g2 = 0; g2 < 8; g2++) s += bufT[g2][d];
  }
  red[side][d] = s;
  __syncthreads();

  int cntv = end - start;
  float inv = cntv ? 1.f / (float)cntv : 0.f;
  const float* w = side ? wR : wL;
  float acc = 0.f;
#pragma unroll 8
  for (int k = 0; k < D; k++) acc = fmaf(red[side][k], w[k * D + d], acc);
  float rv = fmaxf(acc * inv, 0.f);
  if (side == 0) aR[(size_t)r * D + d] = rv * watt[d];
  else           bR[(size_t)r * D + d] = rv * watt[D + d];
}

// ---------------------------------------------------------------------------
// fused edge attention + aggregation + finalize; bf16 reads, 2x unrolled.
// ---------------------------------------------------------------------------
template <bool ENT_IS_BASE, bool WF32>
__global__ __launch_bounds__(256) void k_row_edge(
    const short* __restrict__ ent16, const short* __restrict__ base16,
    const float* __restrict__ aR, const float* __restrict__ bR,
    const int* __restrict__ rowOff, const unsigned* __restrict__ edgeCR,
    float* __restrict__ outf, short* __restrict__ out16)
{
  int gg = blockIdx.x * 256 + threadIdx.x;
  int row = gg >> 5;
  int q = gg & 5 * 0 + (gg & 31);   // q = gg & 31
  q = gg & 31;
  if (row >= E_N) return;
  int start = (row == 0) ? 0 : rowOff[row - 1];
  int end   = rowOff[row];

  ushort4v bu = *(const ushort4v*)&base16[(size_t)row * D + q * 4];
  float4 b4;
  b4.x = b2f(bu[0]); b4.y = b2f(bu[1]); b4.z = b2f(bu[2]); b4.w = b2f(bu[3]);
  float4 er;
  if (ENT_IS_BASE) {
    er = b4;
  } else {
    ushort4v e = *(const ushort4v*)&ent16[(size_t)row * D + q * 4];
    er.x = b2f(e[0]); er.y = b2f(e[1]); er.z = b2f(e[2]); er.w = b2f(e[3]);
  }
  float4 acc = {0.f, 0.f, 0.f, 0.f};
  float rowsum = 0.f;

  int j = start;
  for (; j + 1 < end; j += 2) {
    unsigned cr0 = edgeCR[j];
    unsigned cr1 = edgeCR[j + 1];
    int col0 = cr0 & 0x3FFFF, rel0 = cr0 >> 18;
    int col1 = cr1 & 0x3FFFF, rel1 = cr1 >> 18;
    ushort4v e0 = *(const ushort4v*)&ent16[(size_t)col0 * D + q * 4];
    ushort4v e1 = *(const ushort4v*)&ent16[(size_t)col1 * D + q * 4];
    float4 a0 = *(const float4*)&aR[(size_t)rel0 * D + q * 4];
    float4 c0 = *(const float4*)&bR[(size_t)rel0 * D + q * 4];
    float4 a1 = *(const float4*)&aR[(size_t)rel1 * D + q * 4];
    float4 c1 = *(const float4*)&bR[(size_t)rel1 * D + q * 4];
    float4 ec0, ec1;
    ec0.x = b2f(e0[0]); ec0.y = b2f(e0[1]); ec0.z = b2f(e0[2]); ec0.w = b2f(e0[3]);
    ec1.x = b2f(e1[0]); ec1.y = b2f(e1[1]); ec1.z = b2f(e1[2]); ec1.w = b2f(e1[3]);
    float p0 = er.x * a0.x + er.y * a0.y + er.z * a0.z + er.w * a0.w
             + ec0.x * c0.x + ec0.y * c0.y + ec0.z * c0.z + ec0.w * c0.w;
    float p1 = er.x * a1.x + er.y * a1.y + er.z * a1.z + er.w * a1.w
             + ec1.x * c1.x + ec1.y * c1.y + ec1.z * c1.z + ec1.w * c1.w;
#pragma unroll
    for (int m = 16; m >= 1; m >>= 1) {
      p0 += __shfl_xor(p0, m, 64);
      p1 += __shfl_xor(p1, m, 64);
    }
    float l0 = (p0 >= 0.f) ? p0 : ALPHA_L * p0;
    float l1 = (p1 >= 0.f) ? p1 : ALPHA_L * p1;
    float att0 = expf(-l0);
    float att1 = expf(-l1);
    acc.x = fmaf(att0, ec0.x, acc.x); acc.y = fmaf(att0, ec0.y, acc.y);
    acc.z = fmaf(att0, ec0.z, acc.z); acc.w = fmaf(att0, ec0.w, acc.w);
    acc.x = fmaf(att1, ec1.x, acc.x); acc.y = fmaf(att1, ec1.y, acc.y);
    acc.z = fmaf(att1, ec1.z, acc.z); acc.w = fmaf(att1, ec1.w, acc.w);
    rowsum += att0 + att1;
  }
  if (j < end) {
    unsigned cr = edgeCR[j];
    int col = cr & 0x3FFFF, rel = cr >> 18;
    ushort4v e = *(const ushort4v*)&ent16[(size_t)col * D + q * 4];
    float4 a4 = *(const float4*)&aR[(size_t)rel * D + q * 4];
    float4 c4 = *(const float4*)&bR[(size_t)rel * D + q * 4];
    float4 ec;
    ec.x = b2f(e[0]); ec.y = b2f(e[1]); ec.z = b2f(e[2]); ec.w = b2f(e[3]);
    float p = er.x * a4.x + er.y * a4.y + er.z * a4.z + er.w * a4.w
            + ec.x * c4.x + ec.y * c4.y + ec.z * c4.z + ec.w * c4.w;
#pragma unroll
    for (int m = 16; m >= 1; m >>= 1) p += __shfl_xor(p, m, 64);
    float lk = (p >= 0.f) ? p : ALPHA_L * p;
    float att = expf(-lk);
    acc.x = fmaf(att, ec.x, acc.x); acc.y = fmaf(att, ec.y, acc.y);
    acc.z = fmaf(att, ec.z, acc.z); acc.w = fmaf(att, ec.w, acc.w);
    rowsum += att;
  }
  float inv = (rowsum == 0.f) ? 0.f : 1.f / rowsum;
  float4 o;
  o.x = b4.x + BETA * fmaxf(acc.x * inv, 0.f);
  o.y = b4.y + BETA * fmaxf(acc.y * inv, 0.f);
  o.z = b4.z + BETA * fmaxf(acc.z * inv, 0.f);
  o.w = b4.w + BETA * fmaxf(acc.w * inv, 0.f);
  if (WF32) {
    *(float4*)&outf[(size_t)row * D + q * 4] = o;
  } else {
    ushort4v u;
    u[0] = (unsigned short)bfc(o.x);
    u[1] = (unsigned short)bfc(o.y);
    u[2] = (unsigned short)bfc(o.z);
    u[3] = (unsigned short)bfc(o.w);
    *(ushort4v*)&out16[(size_t)row * D + q * 4] = u;
  }
}

// ---------------------------------------------------------------------------
extern "C" void kernel_launch(void* const* d_in, const int* in_sizes, int n_in,
                              void* d_out, int out_size, void* d_ws, size_t ws_size,
                              hipStream_t stream)
{
  const float* embed = (const float*)d_in[0];
  const float* wname = (const float*)d_in[1];
  const float* bname = (const float*)d_in[2];
  const float* wL    = (const float*)d_in[3];
  const float* wR    = (const float*)d_in[4];
  const float* watt  = (const float*)d_in[5];
  const int*   th    = (const int*)d_in[6];
  const int*   tr    = (const int*)d_in[7];
  const int*   tt    = (const int*)d_in[8];
  float* out = (float*)d_out;

  char* ws = (char*)d_ws;
  size_t off = 0;
  auto alloc = [&](size_t bytes) -> void* {
    void* p = ws + off;
    off = (off + bytes + 255) & ~(size_t)255;
    return p;
  };
  short*    name16 = (short*)alloc((size_t)E_N * D * 2);
  short*    gat16  = (short*)alloc((size_t)E_N * D * 2);
  float*    aR     = (float*)alloc((size_t)R_N * D * 4);
  float*    bR     = (float*)alloc((size_t)R_N * D * 4);
  int*      relDeg = (int*)alloc((size_t)R_N * 4);
  int*      relOff = (int*)alloc((size_t)R_N * 4);
  int*      rowDeg = (int*)alloc((size_t)E_N * 4);
  int*      rowOff = (int*)alloc((size_t)E_N * 4);
  int*      relIdx = (int*)alloc((size_t)NT * 4);
  unsigned* edgeCR = (unsigned*)alloc((size_t)NE * 4);
  int*      part   = (int*)alloc((size_t)256 * 4);
  short*    WtG    = (short*)alloc((size_t)D * KP * 2);

  // name embedding GEMM (bf16 MFMA, chunked W-LDS)
  k_prep_w<<<(D * KP + 255) / 256, 256, 0, stream>>>(wname, WtG);
  k_name_mfma<<<(E_N + RPB - 1) / RPB, 256, 0, stream>>>(embed, WtG, bname,
                                                         name16);

  // CSR build (layer-invariant); k_zero replaces hipMemsetAsync (runtime
  // fill kernel for the 800KB buffer ran at 6 GB/s = 132 us!)
  k_zero<<<(E_N / 4 + 255) / 256, 256, 0, stream>>>((int4*)relDeg, (int4*)rowDeg);
  k_hist<<<(NT + 255) / 256, 256, 0, stream>>>(th, tr, tt, relDeg, rowDeg);
  k_scan_block<<<1, SCB, 0, stream>>>(relDeg, relOff, nullptr, R_N);
  int nblk = (E_N + SCB - 1) / SCB;
  k_scan_block<<<nblk, SCB, 0, stream>>>(rowDeg, rowOff, part, E_N);
  k_scan_block<<<1, SCB, 0, stream>>>(part, part, nullptr, nblk);
  k_scan_add<<<nblk, SCB, 0, stream>>>(rowOff, part, E_N);
  k_scatter<<<(NT + 255) / 256, 256, 0, stream>>>(th, tr, tt, relOff, rowOff,
                                                  relIdx, edgeCR);

  // layer 1: ent = base = name16, emit gat16
  k_rel_fused<<<R_N, 256, 0, stream>>>(name16, th, tt, relIdx, relOff,
                                       wL, wR, watt, aR, bR);
  k_row_edge<true, false><<<(E_N * 32) / 256, 256, 0, stream>>>(
      name16, name16, aR, bR, rowOff, edgeCR, nullptr, gat16);

  // layer 2: ent = gat16, base = name16, emit f32 out
  k_rel_fused<<<R_N, 256, 0, stream>>>(gat16, th, tt, relIdx, relOff,
                                       wL, wR, watt, aR, bR);
  k_row_edge<false, true><<<(E_N * 32) / 256, 256, 0, stream>>>(
      gat16, name16, aR, bR, rowOff, edgeCR, out, nullptr);
}

// Round 8
// 383.247 us; speedup vs baseline: 1.3084x; 1.0263x over previous
//
#include <hip/hip_runtime.h>
#include <hip/hip_bf16.h>
#include <math.h>

#define E_N 200000
#define R_N 1000
#define D 128
#define NT 200000
#define NE (2*NT)
#define KDIM 300
#define KP 320
#define BETA 0.3f
#define ALPHA_L 0.2f
#define SCB 1024
#define RPB 128          // rows per block in name GEMM (32 per wave)
#define CHUNK_SHORTS (5 * 8 * 64 * 8)   // 5 K-steps of frag-order W = 40KB
#define NBLK 196         // ceil(E_N / SCB)

typedef __attribute__((ext_vector_type(8))) short short8;
typedef __attribute__((ext_vector_type(4))) float f32x4v;
typedef __attribute__((ext_vector_type(4))) unsigned short ushort4v;

__device__ inline short bfc(float f) {
  __hip_bfloat16 b = __float2bfloat16(f);
  return *reinterpret_cast<short*>(&b);
}
__device__ inline float b2f(unsigned short u) {
  return __uint_as_float((unsigned)u << 16);
}

// ---------------------------------------------------------------------------
// Fused: zero relDeg/rowDeg + pack W[300][128] -> bf16 fragment-order (KP=320)
// Element ((s*8+f)*64 + l)*8 + j = W[s*32 + (l>>4)*8 + j][f*16 + (l&15)]
// grid = 196 blocks x 256
// ---------------------------------------------------------------------------
__global__ __launch_bounds__(256) void k_prep_zero(
    const float* __restrict__ W, short* __restrict__ WtG,
    int4* __restrict__ relDeg, int4* __restrict__ rowDeg)
{
  int e = blockIdx.x * 256 + threadIdx.x;
  const int4 z = {0, 0, 0, 0};
  if (e < R_N / 4) relDeg[e] = z;
  if (e < E_N / 4) rowDeg[e] = z;
  if (e < D * KP) {
    int j = e & 7;
    int l = (e >> 3) & 63;
    int fi = e >> 9;
    int s = fi >> 3, f = fi & 7;
    int k = s * 32 + (l >> 4) * 8 + j;
    int c = f * 16 + (l & 15);
    float v = (k < KDIM) ? W[(size_t)k * D + c] : 0.f;
    WtG[e] = bfc(v);
  }
}

// ---------------------------------------------------------------------------
// name16 = bf16(A[E,300] @ W + b). 4 waves x 32 rows; acc = 64 AGPR/wave.
// W staged in LDS in 2 chunks of 40KB (K=160 each).
// ---------------------------------------------------------------------------
__global__ __launch_bounds__(256, 3) void k_name_mfma(
    const float* __restrict__ A, const short* __restrict__ WtG,
    const float* __restrict__ b, short* __restrict__ out16)
{
  __shared__ short Wt[CHUNK_SHORTS];    // 40960 B

  const int tid = threadIdx.x;
  const int wid = tid >> 6;
  const int l   = tid & 63;
  const int lc  = l & 15;
  const int kb  = l >> 4;
  const int rowbase = blockIdx.x * RPB + wid * 32;

  f32x4v acc[2][8];
#pragma unroll
  for (int i = 0; i < 2; i++)
#pragma unroll
    for (int f = 0; f < 8; f++) acc[i][f] = (f32x4v){0.f, 0.f, 0.f, 0.f};

  const float* pa[2];
#pragma unroll
  for (int i = 0; i < 2; i++) {
    int r = rowbase + i * 16 + lc;
    int rl = (r < E_N) ? r : (E_N - 1);
    pa[i] = A + (size_t)rl * KDIM + kb * 8;
  }

  float4 cur[2][2];
#pragma unroll
  for (int i = 0; i < 2; i++) {
    cur[i][0] = *(const float4*)(pa[i] + 0);
    cur[i][1] = *(const float4*)(pa[i] + 4);
  }

#pragma unroll
  for (int c = 0; c < 2; c++) {
    if (c == 1) __syncthreads();   // protect Wt before restage
    {  // stage chunk c (40KB linear)
      const uint4* src = (const uint4*)(WtG + c * CHUNK_SHORTS);
      uint4* dst = (uint4*)Wt;
#pragma unroll
      for (int i = 0; i < 10; i++) dst[i * 256 + tid] = src[i * 256 + tid];
    }
    __syncthreads();

#pragma unroll
    for (int s5 = 0; s5 < 5; s5++) {
      const int s = c * 5 + s5;
      short8 af[2];
#pragma unroll
      for (int i = 0; i < 2; i++) {
        af[i][0] = bfc(cur[i][0].x); af[i][1] = bfc(cur[i][0].y);
        af[i][2] = bfc(cur[i][0].z); af[i][3] = bfc(cur[i][0].w);
        af[i][4] = bfc(cur[i][1].x); af[i][5] = bfc(cur[i][1].y);
        af[i][6] = bfc(cur[i][1].z); af[i][7] = bfc(cur[i][1].w);
      }
      if (s < 9) {
        if (s == 8) {
          float4 z = {0.f, 0.f, 0.f, 0.f};
#pragma unroll
          for (int i = 0; i < 2; i++) {
            cur[i][0] = (kb <= 1) ? *(const float4*)(pa[i] + 288) : z;
            cur[i][1] = (kb == 0) ? *(const float4*)(pa[i] + 292) : z;
          }
        } else {
          int k = 32 * (s + 1);
#pragma unroll
          for (int i = 0; i < 2; i++) {
            cur[i][0] = *(const float4*)(pa[i] + k);
            cur[i][1] = *(const float4*)(pa[i] + k + 4);
          }
        }
      }
#pragma unroll
      for (int f = 0; f < 8; f++) {
        const short8 bf = *(const short8*)((const char*)Wt + (((s5 * 8 + f) << 6) + l) * 16);
#pragma unroll
        for (int i = 0; i < 2; i++)
          acc[i][f] = __builtin_amdgcn_mfma_f32_16x16x32_bf16(af[i], bf, acc[i][f], 0, 0, 0);
      }
    }
  }

  float bv[8];
#pragma unroll
  for (int f = 0; f < 8; f++) bv[f] = b[f * 16 + lc];

#pragma unroll
  for (int i = 0; i < 2; i++) {
#pragma unroll
    for (int ii = 0; ii < 4; ii++) {
      int row = rowbase + i * 16 + kb * 4 + ii;
      if (row < E_N) {
#pragma unroll
        for (int f = 0; f < 8; f++)
          out16[(size_t)row * D + f * 16 + lc] = bfc(acc[i][f][ii] + bv[f]);
      }
    }
  }
}

// ---------------------------------------------------------------------------
// CSR build
// ---------------------------------------------------------------------------
__global__ __launch_bounds__(256) void k_hist(
    const int* __restrict__ th, const int* __restrict__ tr,
    const int* __restrict__ tt,
    int* __restrict__ relDeg, int* __restrict__ rowDeg)
{
  int i = blockIdx.x * 256 + threadIdx.x;
  if (i >= NT) return;
  atomicAdd(&relDeg[tr[i]], 1);
  atomicAdd(&rowDeg[th[i]], 1);
  atomicAdd(&rowDeg[tt[i]], 1);
}

// blocks 0..NBLK-1: block-scan of rowDeg -> rowOff (+part)
// block NBLK: scan of relDeg -> relOff (R_N <= SCB)
__global__ __launch_bounds__(SCB) void k_scan_both(
    const int* __restrict__ rowDeg, int* __restrict__ rowOff,
    const int* __restrict__ relDeg, int* __restrict__ relOff,
    int* __restrict__ part)
{
  __shared__ int buf[SCB];
  bool isRel = (blockIdx.x == NBLK);
  const int* in = isRel ? relDeg : rowDeg;
  int* outp     = isRel ? relOff : rowOff;
  int n         = isRel ? R_N : E_N;
  int base      = isRel ? 0 : blockIdx.x * SCB;
  int i = base + threadIdx.x;
  int v = (i < n) ? in[i] : 0;
  buf[threadIdx.x] = v;
  __syncthreads();
  for (int off = 1; off < SCB; off <<= 1) {
    int add = (threadIdx.x >= off) ? buf[threadIdx.x - off] : 0;
    __syncthreads();
    buf[threadIdx.x] += add;
    __syncthreads();
  }
  if (i < n) outp[i] = buf[threadIdx.x] - v;   // exclusive
  if (!isRel && threadIdx.x == SCB - 1) part[blockIdx.x] = buf[SCB - 1];
}

__global__ __launch_bounds__(SCB) void k_scan_block(
    const int* __restrict__ in, int* __restrict__ out,
    int* __restrict__ part, int n)
{
  __shared__ int buf[SCB];
  int i = blockIdx.x * SCB + threadIdx.x;
  int v = (i < n) ? in[i] : 0;
  buf[threadIdx.x] = v;
  __syncthreads();
  for (int off = 1; off < SCB; off <<= 1) {
    int add = (threadIdx.x >= off) ? buf[threadIdx.x - off] : 0;
    __syncthreads();
    buf[threadIdx.x] += add;
    __syncthreads();
  }
  if (i < n) out[i] = buf[threadIdx.x] - v;
  if (threadIdx.x == SCB - 1 && part) part[blockIdx.x] = buf[SCB - 1];
}

__global__ __launch_bounds__(SCB) void k_scan_add(
    int* __restrict__ out, const int* __restrict__ part, int n)
{
  int i = blockIdx.x * SCB + threadIdx.x;
  if (i < n) out[i] += part[blockIdx.x];
}

__global__ __launch_bounds__(256) void k_scatter(
    const int* __restrict__ th, const int* __restrict__ tr,
    const int* __restrict__ tt,
    int* __restrict__ relOff, int* __restrict__ rowOff,
    int* __restrict__ relIdx, unsigned* __restrict__ edgeCR)
{
  int i = blockIdx.x * 256 + threadIdx.x;
  if (i >= NT) return;
  int h = th[i], r = tr[i], t = tt[i];
  int p = atomicAdd(&relOff[r], 1);
  relIdx[p] = i;
  int pf = atomicAdd(&rowOff[h], 1);
  edgeCR[pf] = (unsigned)t | ((unsigned)r << 18);
  int pb = atomicAdd(&rowOff[t], 1);
  edgeCR[pb] = (unsigned)h | ((unsigned)r << 18);
}

// ---------------------------------------------------------------------------
// per-relation sums (bf16 gathers, 2x unrolled) + mix GEMM -> packed bf16 abR
// abR[r][0..128) = relu(sumH/cnt @ wL)*watt[0:128]; [128..256) = R-side
// ---------------------------------------------------------------------------
__global__ __launch_bounds__(256) void k_rel_fused(
    const short* __restrict__ ent16,
    const int* __restrict__ th, const int* __restrict__ tt,
    const int* __restrict__ relIdx, const int* __restrict__ relOff,
    const float* __restrict__ wL, const float* __restrict__ wR,
    const float* __restrict__ watt,
    unsigned short* __restrict__ abR)
{
  __shared__ float bufH[8][128];
  __shared__ float bufT[8][128];
  __shared__ float red[2][128];
  int r = blockIdx.x;
  int start = (r == 0) ? 0 : relOff[r - 1];
  int end   = relOff[r];
  int g = threadIdx.x >> 5, q = threadIdx.x & 31;

  float4 aH = {0.f, 0.f, 0.f, 0.f}, aT = {0.f, 0.f, 0.f, 0.f};
  int j = start + g;
  for (; j + 8 < end; j += 16) {
    int i0 = relIdx[j];
    int i1 = relIdx[j + 8];
    ushort4v eh0 = *(const ushort4v*)&ent16[(size_t)th[i0] * D + q * 4];
    ushort4v et0 = *(const ushort4v*)&ent16[(size_t)tt[i0] * D + q * 4];
    ushort4v eh1 = *(const ushort4v*)&ent16[(size_t)th[i1] * D + q * 4];
    ushort4v et1 = *(const ushort4v*)&ent16[(size_t)tt[i1] * D + q * 4];
    aH.x += b2f(eh0[0]) + b2f(eh1[0]); aH.y += b2f(eh0[1]) + b2f(eh1[1]);
    aH.z += b2f(eh0[2]) + b2f(eh1[2]); aH.w += b2f(eh0[3]) + b2f(eh1[3]);
    aT.x += b2f(et0[0]) + b2f(et1[0]); aT.y += b2f(et0[1]) + b2f(et1[1]);
    aT.z += b2f(et0[2]) + b2f(et1[2]); aT.w += b2f(et0[3]) + b2f(et1[3]);
  }
  if (j < end) {
    int i = relIdx[j];
    ushort4v eh = *(const ushort4v*)&ent16[(size_t)th[i] * D + q * 4];
    ushort4v et = *(const ushort4v*)&ent16[(size_t)tt[i] * D + q * 4];
    aH.x += b2f(eh[0]); aH.y += b2f(eh[1]); aH.z += b2f(eh[2]); aH.w += b2f(eh[3]);
    aT.x += b2f(et[0]); aT.y += b2f(et[1]); aT.z += b2f(et[2]); aT.w += b2f(et[3]);
  }
  *(float4*)&bufH[g][q * 4] = aH;
  *(float4*)&bufT[g][q * 4] = aT;
  __syncthreads();

  int side = threadIdx.x >> 7;
  int d = threadIdx.x & 127;
  float s = 0.f;
  if (side == 0) {
#pragma unroll
    for (int g2 = 0; g2 < 8; g2++) s += bufH[g2][d];
  } else {
#pragma unroll
    for (int g2 = 0; g2 < 8; g2++) s += bufT[g2][d];
  }
  red[side][d] = s;
  __syncthreads();

  int cntv = end - start;
  float inv = cntv ? 1.f / (float)cntv : 0.f;
  const float* w = side ? wR : wL;
  float acc = 0.f;
#pragma unroll 8
  for (int k = 0; k < D; k++) acc = fmaf(red[side][k], w[k * D + d], acc);
  float rv = fmaxf(acc * inv, 0.f);
  abR[(size_t)r * 256 + side * 128 + d] =
      (unsigned short)bfc(rv * watt[side * 128 + d]);
}

// ---------------------------------------------------------------------------
// fused edge attention + aggregation + finalize; bf16 reads incl. abR.
// ---------------------------------------------------------------------------
template <bool ENT_IS_BASE, bool WF32>
__global__ __launch_bounds__(256) void k_row_edge(
    const short* __restrict__ ent16, const short* __restrict__ base16,
    const unsigned short* __restrict__ abR,
    const int* __restrict__ rowOff, const unsigned* __restrict__ edgeCR,
    float* __restrict__ outf, short* __restrict__ out16)
{
  int gg = blockIdx.x * 256 + threadIdx.x;
  int row = gg >> 5;
  int q = gg & 31;
  if (row >= E_N) return;
  int start = (row == 0) ? 0 : rowOff[row - 1];
  int end   = rowOff[row];

  ushort4v bu = *(const ushort4v*)&base16[(size_t)row * D + q * 4];
  float4 b4;
  b4.x = b2f(bu[0]); b4.y = b2f(bu[1]); b4.z = b2f(bu[2]); b4.w = b2f(bu[3]);
  float4 er;
  if (ENT_IS_BASE) {
    er = b4;
  } else {
    ushort4v e = *(const ushort4v*)&ent16[(size_t)row * D + q * 4];
    er.x = b2f(e[0]); er.y = b2f(e[1]); er.z = b2f(e[2]); er.w = b2f(e[3]);
  }
  float4 acc = {0.f, 0.f, 0.f, 0.f};
  float rowsum = 0.f;

  int j = start;
  for (; j + 1 < end; j += 2) {
    unsigned cr0 = edgeCR[j];
    unsigned cr1 = edgeCR[j + 1];
    int col0 = cr0 & 0x3FFFF, rel0 = cr0 >> 18;
    int col1 = cr1 & 0x3FFFF, rel1 = cr1 >> 18;
    ushort4v e0 = *(const ushort4v*)&ent16[(size_t)col0 * D + q * 4];
    ushort4v e1 = *(const ushort4v*)&ent16[(size_t)col1 * D + q * 4];
    ushort4v a0u = *(const ushort4v*)&abR[(size_t)rel0 * 256 + q * 4];
    ushort4v c0u = *(const ushort4v*)&abR[(size_t)rel0 * 256 + 128 + q * 4];
    ushort4v a1u = *(const ushort4v*)&abR[(size_t)rel1 * 256 + q * 4];
    ushort4v c1u = *(const ushort4v*)&abR[(size_t)rel1 * 256 + 128 + q * 4];
    float4 ec0, ec1;
    ec0.x = b2f(e0[0]); ec0.y = b2f(e0[1]); ec0.z = b2f(e0[2]); ec0.w = b2f(e0[3]);
    ec1.x = b2f(e1[0]); ec1.y = b2f(e1[1]); ec1.z = b2f(e1[2]); ec1.w = b2f(e1[3]);
    float p0 = er.x * b2f(a0u[0]) + er.y * b2f(a0u[1])
             + er.z * b2f(a0u[2]) + er.w * b2f(a0u[3])
             + ec0.x * b2f(c0u[0]) + ec0.y * b2f(c0u[1])
             + ec0.z * b2f(c0u[2]) + ec0.w * b2f(c0u[3]);
    float p1 = er.x * b2f(a1u[0]) + er.y * b2f(a1u[1])
             + er.z * b2f(a1u[2]) + er.w * b2f(a1u[3])
             + ec1.x * b2f(c1u[0]) + ec1.y * b2f(c1u[1])
             + ec1.z * b2f(c1u[2]) + ec1.w * b2f(c1u[3]);
#pragma unroll
    for (int m = 16; m >= 1; m >>= 1) {
      p0 += __shfl_xor(p0, m, 64);
      p1 += __shfl_xor(p1, m, 64);
    }
    float l0 = (p0 >= 0.f) ? p0 : ALPHA_L * p0;
    float l1 = (p1 >= 0.f) ? p1 : ALPHA_L * p1;
    float att0 = __expf(-l0);
    float att1 = __expf(-l1);
    acc.x = fmaf(att0, ec0.x, acc.x); acc.y = fmaf(att0, ec0.y, acc.y);
    acc.z = fmaf(att0, ec0.z, acc.z); acc.w = fmaf(att0, ec0.w, acc.w);
    acc.x = fmaf(att1, ec1.x, acc.x); acc.y = fmaf(att1, ec1.y, acc.y);
    acc.z = fmaf(att1, ec1.z, acc.z); acc.w = fmaf(att1, ec1.w, acc.w);
    rowsum += att0 + att1;
  }
  if (j < end) {
    unsigned cr = edgeCR[j];
    int col = cr & 0x3FFFF, rel = cr >> 18;
    ushort4v e = *(const ushort4v*)&ent16[(size_t)col * D + q * 4];
    ushort4v au = *(const ushort4v*)&abR[(size_t)rel * 256 + q * 4];
    ushort4v cu = *(const ushort4v*)&abR[(size_t)rel * 256 + 128 + q * 4];
    float4 ec;
    ec.x = b2f(e[0]); ec.y = b2f(e[1]); ec.z = b2f(e[2]); ec.w = b2f(e[3]);
    float p = er.x * b2f(au[0]) + er.y * b2f(au[1])
            + er.z * b2f(au[2]) + er.w * b2f(au[3])
            + ec.x * b2f(cu[0]) + ec.y * b2f(cu[1])
            + ec.z * b2f(cu[2]) + ec.w * b2f(cu[3]);
#pragma unroll
    for (int m = 16; m >= 1; m >>= 1) p += __shfl_xor(p, m, 64);
    float lk = (p >= 0.f) ? p : ALPHA_L * p;
    float att = __expf(-lk);
    acc.x = fmaf(att, ec.x, acc.x); acc.y = fmaf(att, ec.y, acc.y);
    acc.z = fmaf(att, ec.z, acc.z); acc.w = fmaf(att, ec.w, acc.w);
    rowsum += att;
  }
  float inv = (rowsum == 0.f) ? 0.f : 1.f / rowsum;
  float4 o;
  o.x = b4.x + BETA * fmaxf(acc.x * inv, 0.f);
  o.y = b4.y + BETA * fmaxf(acc.y * inv, 0.f);
  o.z = b4.z + BETA * fmaxf(acc.z * inv, 0.f);
  o.w = b4.w + BETA * fmaxf(acc.w * inv, 0.f);
  if (WF32) {
    *(float4*)&outf[(size_t)row * D + q * 4] = o;
  } else {
    ushort4v u;
    u[0] = (unsigned short)bfc(o.x);
    u[1] = (unsigned short)bfc(o.y);
    u[2] = (unsigned short)bfc(o.z);
    u[3] = (unsigned short)bfc(o.w);
    *(ushort4v*)&out16[(size_t)row * D + q * 4] = u;
  }
}

// ---------------------------------------------------------------------------
extern "C" void kernel_launch(void* const* d_in, const int* in_sizes, int n_in,
                              void* d_out, int out_size, void* d_ws, size_t ws_size,
                              hipStream_t stream)
{
  const float* embed = (const float*)d_in[0];
  const float* wname = (const float*)d_in[1];
  const float* bname = (const float*)d_in[2];
  const float* wL    = (const float*)d_in[3];
  const float* wR    = (const float*)d_in[4];
  const float* watt  = (const float*)d_in[5];
  const int*   th    = (const int*)d_in[6];
  const int*   tr    = (const int*)d_in[7];
  const int*   tt    = (const int*)d_in[8];
  float* out = (float*)d_out;

  char* ws = (char*)d_ws;
  size_t off = 0;
  auto alloc = [&](size_t bytes) -> void* {
    void* p = ws + off;
    off = (off + bytes + 255) & ~(size_t)255;
    return p;
  };
  short*          name16 = (short*)alloc((size_t)E_N * D * 2);
  short*          gat16  = (short*)alloc((size_t)E_N * D * 2);
  unsigned short* abR    = (unsigned short*)alloc((size_t)R_N * 256 * 2);
  int*            relDeg = (int*)alloc((size_t)R_N * 4);
  int*            relOff = (int*)alloc((size_t)R_N * 4);
  int*            rowDeg = (int*)alloc((size_t)E_N * 4);
  int*            rowOff = (int*)alloc((size_t)E_N * 4);
  int*            relIdx = (int*)alloc((size_t)NT * 4);
  unsigned*       edgeCR = (unsigned*)alloc((size_t)NE * 4);
  int*            part   = (int*)alloc((size_t)256 * 4);
  short*          WtG    = (short*)alloc((size_t)D * KP * 2);

  // prep (W pack + deg zero), then name GEMM
  k_prep_zero<<<NBLK, 256, 0, stream>>>(wname, WtG, (int4*)relDeg, (int4*)rowDeg);
  k_name_mfma<<<(E_N + RPB - 1) / RPB, 256, 0, stream>>>(embed, WtG, bname,
                                                         name16);

  // CSR build (layer-invariant)
  k_hist<<<(NT + 255) / 256, 256, 0, stream>>>(th, tr, tt, relDeg, rowDeg);
  k_scan_both<<<NBLK + 1, SCB, 0, stream>>>(rowDeg, rowOff, relDeg, relOff, part);
  k_scan_block<<<1, SCB, 0, stream>>>(part, part, nullptr, NBLK);
  k_scan_add<<<NBLK, SCB, 0, stream>>>(rowOff, part, E_N);
  k_scatter<<<(NT + 255) / 256, 256, 0, stream>>>(th, tr, tt, relOff, rowOff,
                                                  relIdx, edgeCR);

  // layer 1: ent = base = name16, emit gat16
  k_rel_fused<<<R_N, 256, 0, stream>>>(name16, th, tt, relIdx, relOff,
                                       wL, wR, watt, abR);
  k_row_edge<true, false><<<(E_N * 32) / 256, 256, 0, stream>>>(
      name16, name16, abR, rowOff, edgeCR, nullptr, gat16);

  // layer 2: ent = gat16, base = name16, emit f32 out
  k_rel_fused<<<R_N, 256, 0, stream>>>(gat16, th, tt, relIdx, relOff,
                                       wL, wR, watt, abR);
  k_row_edge<false, true><<<(E_N * 32) / 256, 256, 0, stream>>>(
      gat16, name16, abR, rowOff, edgeCR, out, nullptr);
}